// Round 12
// baseline (424.380 us; speedup 1.0000x reference)
//
#include <hip/hip_runtime.h>
#include <hip/hip_bf16.h>
#include <math.h>

#define NN 50000
#define NE 800000
#define C  128
#define NR 8            // dst ranges (XCD-affine via blockIdx%8 heuristic)
#define RNG (NN / NR)
typedef unsigned int u32;
typedef unsigned short u16;

using f32x4  = __attribute__((ext_vector_type(4))) float;
using short8 = __attribute__((ext_vector_type(8))) short;

__device__ __forceinline__ u16 f2bf(float f) {
    u32 u = __float_as_uint(f);
    u32 r = u + 0x7FFFu + ((u >> 16) & 1u);
    return (u16)(r >> 16);
}
__device__ __forceinline__ float bf2f(u16 h) {
    return __uint_as_float(((u32)h) << 16);
}

__device__ __forceinline__ void gload_lds16(const u16* g, u16* l) {
    __builtin_amdgcn_global_load_lds(
        (const __attribute__((address_space(1))) u32*)g,
        (__attribute__((address_space(3))) u32*)l,
        16, 0, 0);
}

// ---------------- CSR build ----------------

__global__ __launch_bounds__(256) void k_hist_x(const int* __restrict__ dst, int* __restrict__ deg, int nE) {
    int r    = blockIdx.x & (NR - 1);
    int base = (blockIdx.x >> 3) * 4096;
    int lo   = r * RNG, hi = lo + RNG;
    #pragma unroll
    for (int it = 0; it < 16; ++it) {
        int e = base + it * 256 + threadIdx.x;
        if (e < nE) {
            int d = dst[e];
            if (d >= lo && d < hi) atomicAdd(&deg[d], 1);
        }
    }
}

__global__ __launch_bounds__(1024) void k_scan_blk(const int* __restrict__ deg, int* __restrict__ rowptr,
                                                   int* __restrict__ bsum, int n) {
    __shared__ int wsum[16];
    int tid = threadIdx.x, lane = tid & 63, wid = tid >> 6;
    int i = blockIdx.x * 1024 + tid;
    int v = (i < n) ? deg[i] : 0;
    int incl = v;
    #pragma unroll
    for (int d = 1; d < 64; d <<= 1) {
        int t = __shfl_up(incl, d, 64);
        if (lane >= d) incl += t;
    }
    if (lane == 63) wsum[wid] = incl;
    __syncthreads();
    int wo = 0;
    #pragma unroll
    for (int w = 0; w < 16; ++w) wo += (w < wid) ? wsum[w] : 0;
    if (i < n) rowptr[i + 1] = wo + incl;
    if (tid == 1023) bsum[blockIdx.x] = wo + incl;
}

__global__ void k_scan_sums(int* __restrict__ bsum, int nb) {
    int lane = threadIdx.x;
    int v = (lane < nb) ? bsum[lane] : 0;
    int incl = v;
    #pragma unroll
    for (int d = 1; d < 64; d <<= 1) {
        int t = __shfl_up(incl, d, 64);
        if (lane >= d) incl += t;
    }
    if (lane < nb) bsum[lane] = incl - v;  // exclusive
}

__global__ __launch_bounds__(1024) void k_scan_add(int* __restrict__ rowptr, const int* __restrict__ bsum, int n) {
    int i = blockIdx.x * 1024 + threadIdx.x;
    if (i == 0) rowptr[0] = 0;
    if (i < n) rowptr[i + 1] += bsum[blockIdx.x];
}

__global__ __launch_bounds__(256) void k_fill_x(const int* __restrict__ src, const int* __restrict__ dst,
                                                const int* __restrict__ rowptr, int* __restrict__ deg,
                                                u16* __restrict__ esrc, int nE) {
    int r    = blockIdx.x & (NR - 1);
    int base = (blockIdx.x >> 3) * 4096;
    int lo   = r * RNG, hi = lo + RNG;
    #pragma unroll
    for (int it = 0; it < 16; ++it) {
        int e = base + it * 256 + threadIdx.x;
        if (e < nE) {
            int d = dst[e];
            if (d >= lo && d < hi) {
                int old = atomicSub(&deg[d], 1);
                esrc[rowptr[d + 1] - old] = (u16)src[e];
            }
        }
    }
}

// ---------------- fp32 -> packed bf16 (hi plane) + deg zeroing ----------------
__global__ void k_cvt(const float* __restrict__ in, u32* __restrict__ oh, int* __restrict__ deg, int n64) {
    int i = blockIdx.x * 256 + threadIdx.x;
    if (i < NN) deg[i] = 0;
    if (i < n64) {
        float2 v = *(const float2*)(in + (size_t)i * 2);
        oh[i] = ((u32)f2bf(v.x)) | (((u32)f2bf(v.y)) << 16);
    }
}

// ---------------- weight pack (hi plane only), all 5 layers ----------------
struct PackArgs {
    const float* Wl[5]; const float* Wr[5];
    u16* Wh[5];
};
__global__ void k_packw5(PackArgs pa) {
    int L   = blockIdx.y;
    int idx = blockIdx.x * 256 + threadIdx.x;
    if (idx >= 128 * 256) return;
    int j = idx & 7, l = (idx >> 3) & 63, s = (idx >> 9) & 7, t = idx >> 12;
    int nrow = t * 16 + (l & 15);
    int k    = s * 32 + (l >> 4) * 8 + j;
    float v  = (k < 128) ? pa.Wl[L][nrow * 128 + k] : pa.Wr[L][nrow * 128 + (k - 128)];
    pa.Wh[L][idx] = f2bf(v);
}

// ---------------- fused gather (segment max -> LDS) ----------------
#define UPK(w_, lo_, hi_) { lo_ = fmaxf(lo_, __uint_as_float((w_) << 16)); \
                            hi_ = fmaxf(hi_, __uint_as_float((w_) & 0xFFFF0000u)); }

// Each wave gathers its own 32 rows into swizzled LDS [128][64] u32.
// Swizzle: 16B-slot index ^= (lrow & 15)  -> read-side conflict ~4-way.
__device__ __forceinline__ void gather_rows(
        const u32* __restrict__ gp, const int* __restrict__ rowptr,
        const u16* __restrict__ esrc, u32* sagg, int m0w, int wave, int lane, int n) {
    #pragma unroll 1
    for (int i = 0; i < 32; ++i) {
        int row = m0w + i;
        u32 r = 0u;
        if (row < n) {
            int beg = rowptr[row], end = rowptr[row + 1];
            if (end > beg) {
                float mlo = -INFINITY, mhi = -INFINITY;
                int last = end - 1;
                for (int e = beg; e < end; e += 8) {
                    int e1 = e + 1 > last ? last : e + 1;
                    int e2 = e + 2 > last ? last : e + 2;
                    int e3 = e + 3 > last ? last : e + 3;
                    int e4 = e + 4 > last ? last : e + 4;
                    int e5 = e + 5 > last ? last : e + 5;
                    int e6 = e + 6 > last ? last : e + 6;
                    int e7 = e + 7 > last ? last : e + 7;
                    u32 w0 = gp[((size_t)esrc[e]  << 6) + lane];
                    u32 w1 = gp[((size_t)esrc[e1] << 6) + lane];
                    u32 w2 = gp[((size_t)esrc[e2] << 6) + lane];
                    u32 w3 = gp[((size_t)esrc[e3] << 6) + lane];
                    u32 w4 = gp[((size_t)esrc[e4] << 6) + lane];
                    u32 w5 = gp[((size_t)esrc[e5] << 6) + lane];
                    u32 w6 = gp[((size_t)esrc[e6] << 6) + lane];
                    u32 w7 = gp[((size_t)esrc[e7] << 6) + lane];
                    UPK(w0, mlo, mhi) UPK(w1, mlo, mhi) UPK(w2, mlo, mhi) UPK(w3, mlo, mhi)
                    UPK(w4, mlo, mhi) UPK(w5, mlo, mhi) UPK(w6, mlo, mhi) UPK(w7, mlo, mhi)
                }
                r = (__float_as_uint(mlo) >> 16) | (__float_as_uint(mhi) & 0xFFFF0000u);
            }
        }
        int lrow = wave * 32 + i;
        sagg[lrow * 64 + ((((lane >> 2) ^ (lrow & 15)) << 2) | (lane & 3))] = r;
    }
}

// ---------------- fused gather+GEMM body ----------------
// out[m,:] = relu( agg(gp)[m,:] @ Wl^T + Xh[m,:] @ Wr^T + b ) (bf16 weights/activations)
// HEAD: additionally reduce with hw/hb into hout[m] (and skip plane write).
template<int HEAD>
__device__ __forceinline__ void fused_body(
        const u32* __restrict__ gp, const u16* __restrict__ Xh,
        const u16* __restrict__ Wh, const float* __restrict__ bias,
        u32* __restrict__ outh,
        const float* __restrict__ hw, const float* __restrict__ hb,
        float* __restrict__ hout,
        const int* __restrict__ rowptr, const u16* __restrict__ esrc,
        int n, int bid, u32* sagg, u16 (*smw)[4096]) {
    int tid  = threadIdx.x;
    int wave = tid >> 6, lane = tid & 63;
    int rit  = lane & 15, kgrp = lane >> 4;
    int m0w  = bid * 128 + wave * 32;

    gather_rows(gp, rowptr, esrc, sagg, m0w, wave, lane, n);

    int ar0 = m0w + rit;      if (ar0 > n - 1) ar0 = n - 1;
    int ar1 = m0w + 16 + rit; if (ar1 > n - 1) ar1 = n - 1;
    short8 xh0[4], xh1[4];
    #pragma unroll
    for (int s = 0; s < 4; ++s) {
        xh0[s] = *(const short8*)(Xh + (size_t)ar0 * C + s * 32 + kgrp * 8);
        xh1[s] = *(const short8*)(Xh + (size_t)ar1 * C + s * 32 + kgrp * 8);
    }

    #define STAGEH(s_, b_) do {                                                  \
        _Pragma("unroll")                                                        \
        for (int q = 0; q < 2; ++q) {                                            \
            int tt = wave * 2 + q;                                               \
            const u16* g = Wh + (((tt << 3) + (s_)) << 9) + (lane << 3);         \
            gload_lds16(g, &smw[b_][tt << 9]);                                   \
        }                                                                        \
    } while (0)

    f32x4 acc0[8], acc1[8];
    #pragma unroll
    for (int t = 0; t < 8; ++t) {
        acc0[t] = (f32x4){0.f, 0.f, 0.f, 0.f};
        acc1[t] = (f32x4){0.f, 0.f, 0.f, 0.f};
    }

    STAGEH(0, 0);
    __syncthreads();

    const u32* sa0 = sagg + (size_t)(wave * 32 + rit) * 64;
    const u32* sa1 = sa0 + 16 * 64;

    #pragma unroll
    for (int s = 0; s < 8; ++s) {
        if (s < 7) STAGEH(s + 1, (s + 1) & 1);
        const u16* base = smw[s & 1];
        short8 f0, f1;
        if (s < 4) {
            int sl = ((s << 2) + kgrp) ^ rit;
            f0 = *(const short8*)(sa0 + (sl << 2));
            f1 = *(const short8*)(sa1 + (sl << 2));
        } else {
            f0 = xh0[s - 4];
            f1 = xh1[s - 4];
        }
        #pragma unroll
        for (int t = 0; t < 8; ++t) {
            short8 wv = *(const short8*)(base + (t << 9) + (lane << 3));
            acc0[t] = __builtin_amdgcn_mfma_f32_16x16x32_bf16(f0, wv, acc0[t], 0, 0, 0);
            acc1[t] = __builtin_amdgcn_mfma_f32_16x16x32_bf16(f1, wv, acc1[t], 0, 0, 0);
        }
        if (s < 7) __syncthreads();
    }
    #undef STAGEH

    if (HEAD) {
        float hsA[4] = {0.f, 0.f, 0.f, 0.f}, hsB[4] = {0.f, 0.f, 0.f, 0.f};
        #pragma unroll
        for (int t = 0; t < 8; ++t) {
            int col = t * 16 + rit;
            float b = bias[col], w = hw[col];
            #pragma unroll
            for (int j = 0; j < 4; ++j) {
                hsA[j] += fmaxf(acc0[t][j] + b, 0.f) * w;
                hsB[j] += fmaxf(acc1[t][j] + b, 0.f) * w;
            }
        }
        #pragma unroll
        for (int msk = 1; msk < 16; msk <<= 1) {
            #pragma unroll
            for (int j = 0; j < 4; ++j) {
                hsA[j] += __shfl_xor(hsA[j], msk, 64);
                hsB[j] += __shfl_xor(hsB[j], msk, 64);
            }
        }
        if (rit == 0) {
            float hbv = hb[0];
            #pragma unroll
            for (int j = 0; j < 4; ++j) {
                int rA = m0w + kgrp * 4 + j;
                int rB = rA + 16;
                if (rA < n) hout[rA] = hsA[j] + hbv;
                if (rB < n) hout[rB] = hsB[j] + hbv;
            }
        }
    } else {
        #pragma unroll
        for (int g = 0; g < 2; ++g) {
            int rbase = m0w + g * 16 + kgrp * 4;
            #pragma unroll
            for (int t = 0; t < 8; ++t) {
                int col = t * 16 + rit;
                float b = bias[col];
                #pragma unroll
                for (int j = 0; j < 4; ++j) {
                    int rr = rbase + j;
                    float v = fmaxf((g ? acc1[t][j] : acc0[t][j]) + b, 0.f);
                    float pv = __shfl_xor(v, 1, 64);
                    if (!(rit & 1) && rr < n)
                        outh[(size_t)rr * 64 + (col >> 1)] = ((u32)f2bf(v)) | (((u32)f2bf(pv)) << 16);
                }
            }
        }
    }
}

// single fused layer (L1)
__global__ __launch_bounds__(256, 3) void k_fused(
        const u32* __restrict__ gp, const u16* __restrict__ Xh,
        const u16* __restrict__ Wh, const float* __restrict__ bias, u32* __restrict__ outh,
        const int* __restrict__ rowptr, const u16* __restrict__ esrc, int n) {
    __shared__ u32 sagg[128 * 64];
    __shared__ __align__(16) u16 smw[2][4096];
    fused_body<0>(gp, Xh, Wh, bias, outh, nullptr, nullptr, nullptr,
                  rowptr, esrc, n, blockIdx.x, sagg, smw);
}

// both head layers (L3 rt + L3 md) in one dispatch
__global__ __launch_bounds__(256, 3) void k_fused_heads(
        const u32* __restrict__ gpA, const u16* __restrict__ XhA,
        const u16* __restrict__ WhA, const float* __restrict__ biasA,
        const float* __restrict__ hwA, const float* __restrict__ hbA, float* __restrict__ houtA,
        const u32* __restrict__ gpB, const u16* __restrict__ XhB,
        const u16* __restrict__ WhB, const float* __restrict__ biasB,
        const float* __restrict__ hwB, const float* __restrict__ hbB, float* __restrict__ houtB,
        const int* __restrict__ rowptr, const u16* __restrict__ esrc, int n) {
    __shared__ u32 sagg[128 * 64];
    __shared__ __align__(16) u16 smw[2][4096];
    int nb = (n + 127) >> 7;
    int br = blockIdx.x >= nb;
    int bid = blockIdx.x - br * nb;
    const u32* gp   = br ? gpB   : gpA;
    const u16* Xh   = br ? XhB   : XhA;
    const u16* Wh   = br ? WhB   : WhA;
    const float* bi = br ? biasB : biasA;
    const float* hw = br ? hwB   : hwA;
    const float* hb = br ? hbB   : hbA;
    float* hout     = br ? houtB : houtA;
    fused_body<1>(gp, Xh, Wh, bi, nullptr, hw, hb, hout,
                  rowptr, esrc, n, bid, sagg, smw);
}

// dual fused layer (L2: rt1 + mv1 share one gather of mv)
__global__ __launch_bounds__(256, 2) void k_fused2(
        const u32* __restrict__ gp, const u16* __restrict__ Xh,
        const u16* __restrict__ Wh1, const float* __restrict__ b1, u32* __restrict__ out1,
        const u16* __restrict__ Wh2, const float* __restrict__ b2, u32* __restrict__ out2,
        const int* __restrict__ rowptr, const u16* __restrict__ esrc, int n) {
    __shared__ u32 sagg[128 * 64];
    __shared__ __align__(16) u16 smw[2][8192];  // 2 sets x 8 slices x 512 u16
    int tid  = threadIdx.x;
    int wave = tid >> 6, lane = tid & 63;
    int rit  = lane & 15, kgrp = lane >> 4;
    int m0w  = blockIdx.x * 128 + wave * 32;

    gather_rows(gp, rowptr, esrc, sagg, m0w, wave, lane, n);

    int ar0 = m0w + rit;      if (ar0 > n - 1) ar0 = n - 1;
    int ar1 = m0w + 16 + rit; if (ar1 > n - 1) ar1 = n - 1;
    short8 xh0[4], xh1[4];
    #pragma unroll
    for (int s = 0; s < 4; ++s) {
        xh0[s] = *(const short8*)(Xh + (size_t)ar0 * C + s * 32 + kgrp * 8);
        xh1[s] = *(const short8*)(Xh + (size_t)ar1 * C + s * 32 + kgrp * 8);
    }

    #define STAGE2H(s_, b_) do {                                                 \
        _Pragma("unroll")                                                        \
        for (int q = 0; q < 4; ++q) {                                            \
            int kk = wave * 4 + q;                                               \
            int set = kk >> 3, tt = kk & 7;                                      \
            const u16* g = (set ? Wh2 : Wh1) + (((tt << 3) + (s_)) << 9) + (lane << 3); \
            gload_lds16(g, &smw[b_][set * 4096 + (tt << 9)]);                    \
        }                                                                        \
    } while (0)

    f32x4 accA0[8], accA1[8], accB0[8], accB1[8];
    #pragma unroll
    for (int t = 0; t < 8; ++t) {
        accA0[t] = (f32x4){0.f, 0.f, 0.f, 0.f};
        accA1[t] = (f32x4){0.f, 0.f, 0.f, 0.f};
        accB0[t] = (f32x4){0.f, 0.f, 0.f, 0.f};
        accB1[t] = (f32x4){0.f, 0.f, 0.f, 0.f};
    }

    STAGE2H(0, 0);
    __syncthreads();

    const u32* sa0 = sagg + (size_t)(wave * 32 + rit) * 64;
    const u32* sa1 = sa0 + 16 * 64;

    #pragma unroll
    for (int s = 0; s < 8; ++s) {
        if (s < 7) STAGE2H(s + 1, (s + 1) & 1);
        const u16* base = smw[s & 1];
        short8 f0, f1;
        if (s < 4) {
            int sl = ((s << 2) + kgrp) ^ rit;
            f0 = *(const short8*)(sa0 + (sl << 2));
            f1 = *(const short8*)(sa1 + (sl << 2));
        } else {
            f0 = xh0[s - 4];
            f1 = xh1[s - 4];
        }
        #pragma unroll
        for (int t = 0; t < 8; ++t) {
            short8 wa = *(const short8*)(base + (t << 9) + (lane << 3));
            short8 wb = *(const short8*)(base + 4096 + (t << 9) + (lane << 3));  // set 1 at u16 offset 4096
            accA0[t] = __builtin_amdgcn_mfma_f32_16x16x32_bf16(f0, wa, accA0[t], 0, 0, 0);
            accA1[t] = __builtin_amdgcn_mfma_f32_16x16x32_bf16(f1, wa, accA1[t], 0, 0, 0);
            accB0[t] = __builtin_amdgcn_mfma_f32_16x16x32_bf16(f0, wb, accB0[t], 0, 0, 0);
            accB1[t] = __builtin_amdgcn_mfma_f32_16x16x32_bf16(f1, wb, accB1[t], 0, 0, 0);
        }
        if (s < 7) __syncthreads();
    }
    #undef STAGE2H

    #pragma unroll
    for (int e = 0; e < 2; ++e) {
        const float* bb = e ? b2 : b1;
        u32* oo = e ? out2 : out1;
        #pragma unroll
        for (int g = 0; g < 2; ++g) {
            int rbase = m0w + g * 16 + kgrp * 4;
            #pragma unroll
            for (int t = 0; t < 8; ++t) {
                int col = t * 16 + rit;
                float b = bb[col];
                #pragma unroll
                for (int j = 0; j < 4; ++j) {
                    int rr = rbase + j;
                    float acv = e ? (g ? accB1[t][j] : accB0[t][j])
                                  : (g ? accA1[t][j] : accA0[t][j]);
                    float v = fmaxf(acv + b, 0.f);
                    float pv = __shfl_xor(v, 1, 64);
                    if (!(rit & 1) && rr < n)
                        oo[(size_t)rr * 64 + (col >> 1)] = ((u32)f2bf(v)) | (((u32)f2bf(pv)) << 16);
                }
            }
        }
    }
}

// ---------------- launch ----------------

extern "C" void kernel_launch(void* const* d_in, const int* in_sizes, int n_in,
                              void* d_out, int out_size, void* d_ws, size_t ws_size,
                              hipStream_t stream) {
    const float* x     = (const float*)d_in[0];
    const int*   ei    = (const int*)d_in[1];
    const int*   src   = ei;
    const int*   dstp  = ei + NE;
    const float* sWl   = (const float*)d_in[2];
    const float* sB    = (const float*)d_in[3];
    const float* sWr   = (const float*)d_in[4];
    const float* rt1Wl = (const float*)d_in[5];
    const float* rt1B  = (const float*)d_in[6];
    const float* rt1Wr = (const float*)d_in[7];
    const float* rt2Wl = (const float*)d_in[8];
    const float* rt2B  = (const float*)d_in[9];
    const float* rt2Wr = (const float*)d_in[10];
    const float* rt3W  = (const float*)d_in[11];
    const float* rt3B  = (const float*)d_in[12];
    const float* mv1Wl = (const float*)d_in[13];
    const float* mv1B  = (const float*)d_in[14];
    const float* mv1Wr = (const float*)d_in[15];
    const float* mv2Wl = (const float*)d_in[16];
    const float* mv2B  = (const float*)d_in[17];
    const float* mv2Wr = (const float*)d_in[18];
    const float* mv3W  = (const float*)d_in[19];
    const float* mv3B  = (const float*)d_in[20];
    float* out = (float*)d_out;

    char* ws = (char*)d_ws;
    int* rowptr  = (int*)ws;                  // NN+1
    int* deg     = rowptr + (NN + 1);         // NN
    int* bsum    = deg + NN;                  // 64
    u16* esrc16  = (u16*)(bsum + 64);         // NE u16
    size_t off   = (((size_t)(NN + 1 + NN + 64) * 4 + (size_t)NE * 2) + 255) & ~(size_t)255;
    // 4 bf16 planes: x, mv, rt, md
    u32* P[4];
    for (int i = 0; i < 4; ++i) P[i] = (u32*)(ws + off) + (size_t)i * NN * 64;
    u16* wpack = (u16*)(P[3] + (size_t)NN * 64);
    u16* pk[5];
    for (int L = 0; L < 5; ++L) pk[L] = wpack + (size_t)L * 32768;

    const int NB = (NN + 1023) / 1024;
    const int GCH = ((NE + 4095) / 4096) * NR;

    // weight packing (hi-only) + x conversion (also zeroes deg)
    PackArgs pa;
    pa.Wl[0] = sWl;   pa.Wr[0] = sWr;
    pa.Wl[1] = rt1Wl; pa.Wr[1] = rt1Wr;
    pa.Wl[2] = rt2Wl; pa.Wr[2] = rt2Wr;
    pa.Wl[3] = mv1Wl; pa.Wr[3] = mv1Wr;
    pa.Wl[4] = mv2Wl; pa.Wr[4] = mv2Wr;
    for (int L = 0; L < 5; ++L) pa.Wh[L] = pk[L];
    k_packw5<<<dim3(128, 5), 256, 0, stream>>>(pa);
    k_cvt<<<(NN * 64 + 255) / 256, 256, 0, stream>>>(x, P[0], deg, NN * 64);

    // CSR build (range-partitioned, XCD-affine heuristic)
    k_hist_x<<<GCH, 256, 0, stream>>>(dstp, deg, NE);
    k_scan_blk<<<NB, 1024, 0, stream>>>(deg, rowptr, bsum, NN);
    k_scan_sums<<<1, 64, 0, stream>>>(bsum, NB);
    k_scan_add<<<NB, 1024, 0, stream>>>(rowptr, bsum, NN);
    k_fill_x<<<GCH, 256, 0, stream>>>(src, dstp, rowptr, deg, esrc16, NE);

    const int GT = (NN + 127) / 128;  // 391 tiles

    // L1 (shared): mv = relu(sage(x))  [gather x-plane fused]
    k_fused<<<GT, 256, 0, stream>>>(P[0], (const u16*)P[0], pk[0], sB, P[1],
                                    rowptr, esrc16, NN);
    // L2: rt = relu(sage_rt1(mv)), md = relu(sage_mv1(mv))  [one gather of mv]
    k_fused2<<<GT, 256, 0, stream>>>(P[1], (const u16*)P[1],
                                     pk[1], rt1B, P[2],
                                     pk[3], mv1B, P[3],
                                     rowptr, esrc16, NN);
    // L3 both branches + fused 128->1 heads, one dispatch
    k_fused_heads<<<2 * GT, 256, 0, stream>>>(
        P[2], (const u16*)P[2], pk[2], rt2B, rt3W, rt3B, out,
        P[3], (const u16*)P[3], pk[4], mv2B, mv3W, mv3B, out + NN,
        rowptr, esrc16, NN);
}

// Round 13
// 264.172 us; speedup vs baseline: 1.6065x; 1.6065x over previous
//
#include <hip/hip_runtime.h>
#include <hip/hip_bf16.h>
#include <math.h>

#define NN 50000
#define NE 800000
#define C  128
#define NR 8            // dst ranges (XCD-affine via blockIdx%8 heuristic)
#define RNG (NN / NR)
typedef unsigned int u32;
typedef unsigned short u16;

using f32x4  = __attribute__((ext_vector_type(4))) float;
using short8 = __attribute__((ext_vector_type(8))) short;

__device__ __forceinline__ u16 f2bf(float f) {
    u32 u = __float_as_uint(f);
    u32 r = u + 0x7FFFu + ((u >> 16) & 1u);
    return (u16)(r >> 16);
}

__device__ __forceinline__ void gload_lds16(const u16* g, u16* l) {
    __builtin_amdgcn_global_load_lds(
        (const __attribute__((address_space(1))) u32*)g,
        (__attribute__((address_space(3))) u32*)l,
        16, 0, 0);
}

// ---------------- CSR build ----------------

__global__ __launch_bounds__(256) void k_hist_x(const int* __restrict__ dst, int* __restrict__ deg, int nE) {
    int r    = blockIdx.x & (NR - 1);
    int base = (blockIdx.x >> 3) * 4096;
    int lo   = r * RNG, hi = lo + RNG;
    #pragma unroll
    for (int it = 0; it < 16; ++it) {
        int e = base + it * 256 + threadIdx.x;
        if (e < nE) {
            int d = dst[e];
            if (d >= lo && d < hi) atomicAdd(&deg[d], 1);
        }
    }
}

__global__ __launch_bounds__(1024) void k_scan_blk(const int* __restrict__ deg, int* __restrict__ rowptr,
                                                   int* __restrict__ bsum, int n) {
    __shared__ int wsum[16];
    int tid = threadIdx.x, lane = tid & 63, wid = tid >> 6;
    int i = blockIdx.x * 1024 + tid;
    int v = (i < n) ? deg[i] : 0;
    int incl = v;
    #pragma unroll
    for (int d = 1; d < 64; d <<= 1) {
        int t = __shfl_up(incl, d, 64);
        if (lane >= d) incl += t;
    }
    if (lane == 63) wsum[wid] = incl;
    __syncthreads();
    int wo = 0;
    #pragma unroll
    for (int w = 0; w < 16; ++w) wo += (w < wid) ? wsum[w] : 0;
    if (i < n) rowptr[i + 1] = wo + incl;
    if (tid == 1023) bsum[blockIdx.x] = wo + incl;
}

__global__ void k_scan_sums(int* __restrict__ bsum, int nb) {
    int lane = threadIdx.x;
    int v = (lane < nb) ? bsum[lane] : 0;
    int incl = v;
    #pragma unroll
    for (int d = 1; d < 64; d <<= 1) {
        int t = __shfl_up(incl, d, 64);
        if (lane >= d) incl += t;
    }
    if (lane < nb) bsum[lane] = incl - v;  // exclusive
}

__global__ __launch_bounds__(1024) void k_scan_add(int* __restrict__ rowptr, const int* __restrict__ bsum, int n) {
    int i = blockIdx.x * 1024 + threadIdx.x;
    if (i == 0) rowptr[0] = 0;
    if (i < n) rowptr[i + 1] += bsum[blockIdx.x];
}

__global__ __launch_bounds__(256) void k_fill_x(const int* __restrict__ src, const int* __restrict__ dst,
                                                const int* __restrict__ rowptr, int* __restrict__ deg,
                                                u16* __restrict__ esrc, int nE) {
    int r    = blockIdx.x & (NR - 1);
    int base = (blockIdx.x >> 3) * 4096;
    int lo   = r * RNG, hi = lo + RNG;
    #pragma unroll
    for (int it = 0; it < 16; ++it) {
        int e = base + it * 256 + threadIdx.x;
        if (e < nE) {
            int d = dst[e];
            if (d >= lo && d < hi) {
                int old = atomicSub(&deg[d], 1);
                esrc[rowptr[d + 1] - old] = (u16)src[e];
            }
        }
    }
}

// ---------------- fp32 -> packed bf16 (hi plane) + deg zeroing ----------------
__global__ void k_cvt(const float* __restrict__ in, u32* __restrict__ oh, int* __restrict__ deg, int n64) {
    int i = blockIdx.x * 256 + threadIdx.x;
    if (i < NN) deg[i] = 0;
    if (i < n64) {
        float2 v = *(const float2*)(in + (size_t)i * 2);
        oh[i] = ((u32)f2bf(v.x)) | (((u32)f2bf(v.y)) << 16);
    }
}

// ---------------- segment max over packed bf16 ----------------
#define UPK(w_, lo_, hi_) { lo_ = fmaxf(lo_, __uint_as_float((w_) << 16)); \
                            hi_ = fmaxf(hi_, __uint_as_float((w_) & 0xFFFF0000u)); }

__global__ __launch_bounds__(256) void k_segmax_bf(const u32* __restrict__ h2, const int* __restrict__ rowptr,
                                                   const u16* __restrict__ esrc, u32* __restrict__ agg2, int n) {
    int node = blockIdx.x * 4 + (threadIdx.x >> 6);
    int lane = threadIdx.x & 63;
    if (node >= n) return;
    int beg = rowptr[node], end = rowptr[node + 1];
    float mlo = -INFINITY, mhi = -INFINITY;
    int last = end - 1;
    for (int i = beg; i < end; i += 8) {
        int e1 = i + 1 > last ? last : i + 1;
        int e2 = i + 2 > last ? last : i + 2;
        int e3 = i + 3 > last ? last : i + 3;
        int e4 = i + 4 > last ? last : i + 4;
        int e5 = i + 5 > last ? last : i + 5;
        int e6 = i + 6 > last ? last : i + 6;
        int e7 = i + 7 > last ? last : i + 7;
        u32 w0 = h2[((size_t)esrc[i]  << 6) + lane];
        u32 w1 = h2[((size_t)esrc[e1] << 6) + lane];
        u32 w2 = h2[((size_t)esrc[e2] << 6) + lane];
        u32 w3 = h2[((size_t)esrc[e3] << 6) + lane];
        u32 w4 = h2[((size_t)esrc[e4] << 6) + lane];
        u32 w5 = h2[((size_t)esrc[e5] << 6) + lane];
        u32 w6 = h2[((size_t)esrc[e6] << 6) + lane];
        u32 w7 = h2[((size_t)esrc[e7] << 6) + lane];
        UPK(w0, mlo, mhi) UPK(w1, mlo, mhi) UPK(w2, mlo, mhi) UPK(w3, mlo, mhi)
        UPK(w4, mlo, mhi) UPK(w5, mlo, mhi) UPK(w6, mlo, mhi) UPK(w7, mlo, mhi)
    }
    u32 r = 0u;
    if (end > beg)
        r = (__float_as_uint(mlo) >> 16) | (__float_as_uint(mhi) & 0xFFFF0000u);
    __builtin_nontemporal_store(r, &agg2[(size_t)node * 64 + lane]);
}

// dual: two feature arrays over the same edges, 16 gathers in flight
__global__ __launch_bounds__(256) void k_segmax_bf2(const u32* __restrict__ hA, const u32* __restrict__ hB,
                                                    const int* __restrict__ rowptr, const u16* __restrict__ esrc,
                                                    u32* __restrict__ aggA, u32* __restrict__ aggB, int n) {
    int node = blockIdx.x * 4 + (threadIdx.x >> 6);
    int lane = threadIdx.x & 63;
    if (node >= n) return;
    int beg = rowptr[node], end = rowptr[node + 1];
    float alo = -INFINITY, ahi = -INFINITY, blo = -INFINITY, bhi = -INFINITY;
    int last = end - 1;
    for (int i = beg; i < end; i += 8) {
        int e1 = i + 1 > last ? last : i + 1;
        int e2 = i + 2 > last ? last : i + 2;
        int e3 = i + 3 > last ? last : i + 3;
        int e4 = i + 4 > last ? last : i + 4;
        int e5 = i + 5 > last ? last : i + 5;
        int e6 = i + 6 > last ? last : i + 6;
        int e7 = i + 7 > last ? last : i + 7;
        size_t b0 = ((size_t)esrc[i]  << 6) + lane;
        size_t b1 = ((size_t)esrc[e1] << 6) + lane;
        size_t b2 = ((size_t)esrc[e2] << 6) + lane;
        size_t b3 = ((size_t)esrc[e3] << 6) + lane;
        size_t b4 = ((size_t)esrc[e4] << 6) + lane;
        size_t b5 = ((size_t)esrc[e5] << 6) + lane;
        size_t b6 = ((size_t)esrc[e6] << 6) + lane;
        size_t b7 = ((size_t)esrc[e7] << 6) + lane;
        u32 a0 = hA[b0], a1 = hA[b1], a2 = hA[b2], a3 = hA[b3];
        u32 a4 = hA[b4], a5 = hA[b5], a6 = hA[b6], a7 = hA[b7];
        u32 q0 = hB[b0], q1 = hB[b1], q2 = hB[b2], q3 = hB[b3];
        u32 q4 = hB[b4], q5 = hB[b5], q6 = hB[b6], q7 = hB[b7];
        UPK(a0, alo, ahi) UPK(a1, alo, ahi) UPK(a2, alo, ahi) UPK(a3, alo, ahi)
        UPK(a4, alo, ahi) UPK(a5, alo, ahi) UPK(a6, alo, ahi) UPK(a7, alo, ahi)
        UPK(q0, blo, bhi) UPK(q1, blo, bhi) UPK(q2, blo, bhi) UPK(q3, blo, bhi)
        UPK(q4, blo, bhi) UPK(q5, blo, bhi) UPK(q6, blo, bhi) UPK(q7, blo, bhi)
    }
    u32 ra = 0u, rb = 0u;
    if (end > beg) {
        ra = (__float_as_uint(alo) >> 16) | (__float_as_uint(ahi) & 0xFFFF0000u);
        rb = (__float_as_uint(blo) >> 16) | (__float_as_uint(bhi) & 0xFFFF0000u);
    }
    __builtin_nontemporal_store(ra, &aggA[(size_t)node * 64 + lane]);
    __builtin_nontemporal_store(rb, &aggB[(size_t)node * 64 + lane]);
}

// ---------------- weight pack (hi plane only), all 5 layers ----------------
struct PackArgs {
    const float* Wl[5]; const float* Wr[5];
    u16* Wh[5];
};
__global__ void k_packw5(PackArgs pa) {
    int L   = blockIdx.y;
    int idx = blockIdx.x * 256 + threadIdx.x;
    if (idx >= 128 * 256) return;
    int j = idx & 7, l = (idx >> 3) & 63, s = (idx >> 9) & 7, t = idx >> 12;
    int nrow = t * 16 + (l & 15);
    int k    = s * 32 + (l >> 4) * 8 + j;
    float v  = (k < 128) ? pa.Wl[L][nrow * 128 + k] : pa.Wr[L][nrow * 128 + (k - 128)];
    pa.Wh[L][idx] = f2bf(v);
}

// ---------------- GEMM body (hi-only weights, BM=128, M=32/wave) ----------------
// out = relu( A@Wl^T + X@Wr^T + b ) with bf16 A, X, W. HEAD: fused 128->1 head.
template<int HEAD>
__device__ __forceinline__ void gemm_body(
        const u16* __restrict__ Ahi, const u16* __restrict__ Xh,
        const u16* __restrict__ Wh, const float* __restrict__ bias,
        u32* __restrict__ outh,
        const float* __restrict__ hw, const float* __restrict__ hb,
        float* __restrict__ hout, int n, int bid, u16 (*smw)[4096]) {
    int tid  = threadIdx.x;
    int wave = tid >> 6, lane = tid & 63;
    int rit  = lane & 15, kgrp = lane >> 4;
    int m0   = bid * 128 + wave * 32;
    int ar0  = m0 + rit;      if (ar0 > n - 1) ar0 = n - 1;
    int ar1  = m0 + 16 + rit; if (ar1 > n - 1) ar1 = n - 1;

    #define STAGEH(s_, b_) do {                                                  \
        _Pragma("unroll")                                                        \
        for (int q = 0; q < 2; ++q) {                                            \
            int tt = wave * 2 + q;                                               \
            const u16* g = Wh + (((tt << 3) + (s_)) << 9) + (lane << 3);         \
            gload_lds16(g, &smw[b_][tt << 9]);                                   \
        }                                                                        \
    } while (0)

    // fragment preload: 16 x short8 = 64 VGPR
    short8 a0[4], a1[4], xh0[4], xh1[4];
    #pragma unroll
    for (int s = 0; s < 4; ++s) {
        size_t o0 = (size_t)ar0 * C + s * 32 + kgrp * 8;
        size_t o1 = (size_t)ar1 * C + s * 32 + kgrp * 8;
        a0[s]  = *(const short8*)(Ahi + o0);
        a1[s]  = *(const short8*)(Ahi + o1);
        xh0[s] = *(const short8*)(Xh + o0);
        xh1[s] = *(const short8*)(Xh + o1);
    }

    f32x4 acc0[8], acc1[8];
    #pragma unroll
    for (int t = 0; t < 8; ++t) {
        acc0[t] = (f32x4){0.f, 0.f, 0.f, 0.f};
        acc1[t] = (f32x4){0.f, 0.f, 0.f, 0.f};
    }

    STAGEH(0, 0);
    __syncthreads();

    #pragma unroll
    for (int s = 0; s < 8; ++s) {
        if (s < 7) STAGEH(s + 1, (s + 1) & 1);
        const u16* base = smw[s & 1];
        short8 f0 = (s < 4) ? a0[s] : xh0[s - 4];
        short8 f1 = (s < 4) ? a1[s] : xh1[s - 4];
        #pragma unroll
        for (int t = 0; t < 8; ++t) {
            short8 wv = *(const short8*)(base + (t << 9) + (lane << 3));
            acc0[t] = __builtin_amdgcn_mfma_f32_16x16x32_bf16(f0, wv, acc0[t], 0, 0, 0);
            acc1[t] = __builtin_amdgcn_mfma_f32_16x16x32_bf16(f1, wv, acc1[t], 0, 0, 0);
        }
        if (s < 7) __syncthreads();
    }
    #undef STAGEH

    if (HEAD) {
        float hsA[4] = {0.f, 0.f, 0.f, 0.f}, hsB[4] = {0.f, 0.f, 0.f, 0.f};
        #pragma unroll
        for (int t = 0; t < 8; ++t) {
            int col = t * 16 + rit;
            float b = bias[col], w = hw[col];
            #pragma unroll
            for (int j = 0; j < 4; ++j) {
                hsA[j] += fmaxf(acc0[t][j] + b, 0.f) * w;
                hsB[j] += fmaxf(acc1[t][j] + b, 0.f) * w;
            }
        }
        #pragma unroll
        for (int msk = 1; msk < 16; msk <<= 1) {
            #pragma unroll
            for (int j = 0; j < 4; ++j) {
                hsA[j] += __shfl_xor(hsA[j], msk, 64);
                hsB[j] += __shfl_xor(hsB[j], msk, 64);
            }
        }
        if (rit == 0) {
            float hbv = hb[0];
            #pragma unroll
            for (int j = 0; j < 4; ++j) {
                int rA = m0 + kgrp * 4 + j;
                int rB = rA + 16;
                if (rA < n) hout[rA] = hsA[j] + hbv;
                if (rB < n) hout[rB] = hsB[j] + hbv;
            }
        }
    } else {
        #pragma unroll
        for (int g = 0; g < 2; ++g) {
            int rbase = m0 + g * 16 + kgrp * 4;
            #pragma unroll
            for (int t = 0; t < 8; ++t) {
                int col = t * 16 + rit;
                float b = bias[col];
                #pragma unroll
                for (int j = 0; j < 4; ++j) {
                    int rr = rbase + j;
                    float v = fmaxf((g ? acc1[t][j] : acc0[t][j]) + b, 0.f);
                    float pv = __shfl_xor(v, 1, 64);
                    if (!(rit & 1) && rr < n)
                        outh[(size_t)rr * 64 + (col >> 1)] = ((u32)f2bf(v)) | (((u32)f2bf(pv)) << 16);
                }
            }
        }
    }
}

// L1 GEMM
__global__ __launch_bounds__(256, 2) void k_gemm_p(
        const u16* __restrict__ Ahi, const u16* __restrict__ Xh,
        const u16* __restrict__ Wh, const float* __restrict__ bias, u32* __restrict__ outh, int n) {
    __shared__ __align__(16) u16 smw[2][4096];
    gemm_body<0>(Ahi, Xh, Wh, bias, outh, nullptr, nullptr, nullptr, n, blockIdx.x, smw);
}

// merged L3 GEMMs + heads: grid = 2*GT, branch select
__global__ __launch_bounds__(256, 2) void k_gemm_heads(
        const u16* __restrict__ AhiA, const u16* __restrict__ XhA,
        const u16* __restrict__ WhA, const float* __restrict__ biasA,
        const float* __restrict__ hwA, const float* __restrict__ hbA, float* __restrict__ houtA,
        const u16* __restrict__ AhiB, const u16* __restrict__ XhB,
        const u16* __restrict__ WhB, const float* __restrict__ biasB,
        const float* __restrict__ hwB, const float* __restrict__ hbB, float* __restrict__ houtB,
        int n) {
    __shared__ __align__(16) u16 smw[2][4096];
    int nb = (n + 127) >> 7;
    int br = blockIdx.x >= nb;
    int bid = blockIdx.x - br * nb;
    gemm_body<1>(br ? AhiB : AhiA, br ? XhB : XhA, br ? WhB : WhA,
                 br ? biasB : biasA, nullptr,
                 br ? hwB : hwA, br ? hbB : hbA, br ? houtB : houtA,
                 n, bid, smw);
}

// dual-output L2: two weight sets against the same (A, X)
__global__ __launch_bounds__(256, 2) void k_gemm_p2(
        const u16* __restrict__ Ahi, const u16* __restrict__ Xh,
        const u16* __restrict__ Wh1, const float* __restrict__ b1, u32* __restrict__ out1,
        const u16* __restrict__ Wh2, const float* __restrict__ b2, u32* __restrict__ out2, int n) {
    __shared__ __align__(16) u16 smw[2][8192];  // 2 sets x 8 slices x 512 u16
    int tid  = threadIdx.x;
    int wave = tid >> 6, lane = tid & 63;
    int rit  = lane & 15, kgrp = lane >> 4;
    int m0   = blockIdx.x * 128 + wave * 32;
    int ar0  = m0 + rit;      if (ar0 > n - 1) ar0 = n - 1;
    int ar1  = m0 + 16 + rit; if (ar1 > n - 1) ar1 = n - 1;

    #define STAGE2H(s_, b_) do {                                                 \
        _Pragma("unroll")                                                        \
        for (int q = 0; q < 4; ++q) {                                            \
            int kk = wave * 4 + q;                                               \
            int set = kk >> 3, tt = kk & 7;                                      \
            const u16* g = (set ? Wh2 : Wh1) + (((tt << 3) + (s_)) << 9) + (lane << 3); \
            gload_lds16(g, &smw[b_][set * 4096 + (tt << 9)]);                    \
        }                                                                        \
    } while (0)

    short8 a0[4], a1[4], xh0[4], xh1[4];
    #pragma unroll
    for (int s = 0; s < 4; ++s) {
        size_t o0 = (size_t)ar0 * C + s * 32 + kgrp * 8;
        size_t o1 = (size_t)ar1 * C + s * 32 + kgrp * 8;
        a0[s]  = *(const short8*)(Ahi + o0);
        a1[s]  = *(const short8*)(Ahi + o1);
        xh0[s] = *(const short8*)(Xh + o0);
        xh1[s] = *(const short8*)(Xh + o1);
    }

    f32x4 accA0[8], accA1[8], accB0[8], accB1[8];
    #pragma unroll
    for (int t = 0; t < 8; ++t) {
        accA0[t] = (f32x4){0.f, 0.f, 0.f, 0.f};
        accA1[t] = (f32x4){0.f, 0.f, 0.f, 0.f};
        accB0[t] = (f32x4){0.f, 0.f, 0.f, 0.f};
        accB1[t] = (f32x4){0.f, 0.f, 0.f, 0.f};
    }

    STAGE2H(0, 0);
    __syncthreads();

    #pragma unroll
    for (int s = 0; s < 8; ++s) {
        if (s < 7) STAGE2H(s + 1, (s + 1) & 1);
        const u16* base = smw[s & 1];
        short8 f0 = (s < 4) ? a0[s] : xh0[s - 4];
        short8 f1 = (s < 4) ? a1[s] : xh1[s - 4];
        #pragma unroll
        for (int t = 0; t < 8; ++t) {
            short8 wa = *(const short8*)(base + (t << 9) + (lane << 3));
            short8 wb = *(const short8*)(base + 4096 + (t << 9) + (lane << 3));
            accA0[t] = __builtin_amdgcn_mfma_f32_16x16x32_bf16(f0, wa, accA0[t], 0, 0, 0);
            accA1[t] = __builtin_amdgcn_mfma_f32_16x16x32_bf16(f1, wa, accA1[t], 0, 0, 0);
            accB0[t] = __builtin_amdgcn_mfma_f32_16x16x32_bf16(f0, wb, accB0[t], 0, 0, 0);
            accB1[t] = __builtin_amdgcn_mfma_f32_16x16x32_bf16(f1, wb, accB1[t], 0, 0, 0);
        }
        if (s < 7) __syncthreads();
    }
    #undef STAGE2H

    #pragma unroll
    for (int e = 0; e < 2; ++e) {
        const float* bb = e ? b2 : b1;
        u32* oo = e ? out2 : out1;
        #pragma unroll
        for (int g = 0; g < 2; ++g) {
            int rbase = m0 + g * 16 + kgrp * 4;
            #pragma unroll
            for (int t = 0; t < 8; ++t) {
                int col = t * 16 + rit;
                float b = bb[col];
                #pragma unroll
                for (int j = 0; j < 4; ++j) {
                    int rr = rbase + j;
                    float acv = e ? (g ? accB1[t][j] : accB0[t][j])
                                  : (g ? accA1[t][j] : accA0[t][j]);
                    float v = fmaxf(acv + b, 0.f);
                    float pv = __shfl_xor(v, 1, 64);
                    if (!(rit & 1) && rr < n)
                        oo[(size_t)rr * 64 + (col >> 1)] = ((u32)f2bf(v)) | (((u32)f2bf(pv)) << 16);
                }
            }
        }
    }
}

// ---------------- launch ----------------

extern "C" void kernel_launch(void* const* d_in, const int* in_sizes, int n_in,
                              void* d_out, int out_size, void* d_ws, size_t ws_size,
                              hipStream_t stream) {
    const float* x     = (const float*)d_in[0];
    const int*   ei    = (const int*)d_in[1];
    const int*   src   = ei;
    const int*   dstp  = ei + NE;
    const float* sWl   = (const float*)d_in[2];
    const float* sB    = (const float*)d_in[3];
    const float* sWr   = (const float*)d_in[4];
    const float* rt1Wl = (const float*)d_in[5];
    const float* rt1B  = (const float*)d_in[6];
    const float* rt1Wr = (const float*)d_in[7];
    const float* rt2Wl = (const float*)d_in[8];
    const float* rt2B  = (const float*)d_in[9];
    const float* rt2Wr = (const float*)d_in[10];
    const float* rt3W  = (const float*)d_in[11];
    const float* rt3B  = (const float*)d_in[12];
    const float* mv1Wl = (const float*)d_in[13];
    const float* mv1B  = (const float*)d_in[14];
    const float* mv1Wr = (const float*)d_in[15];
    const float* mv2Wl = (const float*)d_in[16];
    const float* mv2B  = (const float*)d_in[17];
    const float* mv2Wr = (const float*)d_in[18];
    const float* mv3W  = (const float*)d_in[19];
    const float* mv3B  = (const float*)d_in[20];
    float* out = (float*)d_out;

    char* ws = (char*)d_ws;
    int* rowptr  = (int*)ws;                  // NN+1
    int* deg     = rowptr + (NN + 1);         // NN
    int* bsum    = deg + NN;                  // 64
    u16* esrc16  = (u16*)(bsum + 64);         // NE u16
    size_t off   = (((size_t)(NN + 1 + NN + 64) * 4 + (size_t)NE * 2) + 255) & ~(size_t)255;
    // 5 bf16 planes, each NN*64 u32 = 12.8 MB
    u32* P[5];
    for (int i = 0; i < 5; ++i) P[i] = (u32*)(ws + off) + (size_t)i * NN * 64;
    u16* wpack = (u16*)(P[4] + (size_t)NN * 64);
    u16* pk[5];
    for (int L = 0; L < 5; ++L) pk[L] = wpack + (size_t)L * 32768;

    const int NB = (NN + 1023) / 1024;
    const int GCH = ((NE + 4095) / 4096) * NR;

    // weight packing (hi-only) + x conversion (also zeroes deg)
    PackArgs pa;
    pa.Wl[0] = sWl;   pa.Wr[0] = sWr;
    pa.Wl[1] = rt1Wl; pa.Wr[1] = rt1Wr;
    pa.Wl[2] = rt2Wl; pa.Wr[2] = rt2Wr;
    pa.Wl[3] = mv1Wl; pa.Wr[3] = mv1Wr;
    pa.Wl[4] = mv2Wl; pa.Wr[4] = mv2Wr;
    for (int L = 0; L < 5; ++L) pa.Wh[L] = pk[L];
    k_packw5<<<dim3(128, 5), 256, 0, stream>>>(pa);
    k_cvt<<<(NN * 64 + 255) / 256, 256, 0, stream>>>(x, P[0], deg, NN * 64);

    // CSR build (range-partitioned, XCD-affine heuristic)
    k_hist_x<<<GCH, 256, 0, stream>>>(dstp, deg, NE);
    k_scan_blk<<<NB, 1024, 0, stream>>>(deg, rowptr, bsum, NN);
    k_scan_sums<<<1, 64, 0, stream>>>(bsum, NB);
    k_scan_add<<<NB, 1024, 0, stream>>>(rowptr, bsum, NN);
    k_fill_x<<<GCH, 256, 0, stream>>>(src, dstp, rowptr, deg, esrc16, NE);

    dim3 gSeg((NN + 3) / 4), bSeg(256);
    const int GT = (NN + 127) / 128;

    // shared layer: agg(x)->P1; mv = relu(sage(x)) -> P2
    k_segmax_bf<<<gSeg, bSeg, 0, stream>>>(P[0], rowptr, esrc16, P[1], NN);
    k_gemm_p<<<GT, 256, 0, stream>>>((const u16*)P[1], (const u16*)P[0],
                                     pk[0], sB, P[2], NN);
    // agg(mv) -> P3; dual GEMM: rt -> P1, md -> P4
    k_segmax_bf<<<gSeg, bSeg, 0, stream>>>(P[2], rowptr, esrc16, P[3], NN);
    k_gemm_p2<<<GT, 256, 0, stream>>>((const u16*)P[3], (const u16*)P[2],
                                      pk[1], rt1B, P[1],
                                      pk[3], mv1B, P[4], NN);
    // fused dual aggregation: agg(rt) -> P0, agg(md) -> P3
    k_segmax_bf2<<<gSeg, bSeg, 0, stream>>>(P[1], P[4], rowptr, esrc16, P[0], P[3], NN);
    // merged L3 + heads (one dispatch, 2*GT blocks)
    k_gemm_heads<<<2 * GT, 256, 0, stream>>>(
        (const u16*)P[0], (const u16*)P[1], pk[2], rt2B, rt3W, rt3B, out,
        (const u16*)P[3], (const u16*)P[4], pk[4], mv2B, mv3W, mv3B, out + NN,
        NN);
}

// Round 14
// 257.736 us; speedup vs baseline: 1.6466x; 1.0250x over previous
//
#include <hip/hip_runtime.h>
#include <hip/hip_bf16.h>
#include <math.h>

#define NN 50000
#define NE 800000
#define C  128
#define NR 8            // dst ranges (XCD-affine via blockIdx%8 heuristic)
#define RNG (NN / NR)
typedef unsigned int u32;
typedef unsigned short u16;

using f32x4  = __attribute__((ext_vector_type(4))) float;
using short8 = __attribute__((ext_vector_type(8))) short;

__device__ __forceinline__ u16 f2bf(float f) {
    u32 u = __float_as_uint(f);
    u32 r = u + 0x7FFFu + ((u >> 16) & 1u);
    return (u16)(r >> 16);
}

__device__ __forceinline__ void gload_lds16(const u16* g, u16* l) {
    __builtin_amdgcn_global_load_lds(
        (const __attribute__((address_space(1))) u32*)g,
        (__attribute__((address_space(3))) u32*)l,
        16, 0, 0);
}

// ---------------- CSR build ----------------

__global__ __launch_bounds__(256) void k_hist_x(const int* __restrict__ dst, int* __restrict__ deg, int nE) {
    int r    = blockIdx.x & (NR - 1);
    int base = (blockIdx.x >> 3) * 4096;
    int lo   = r * RNG, hi = lo + RNG;
    #pragma unroll
    for (int it = 0; it < 16; ++it) {
        int e = base + it * 256 + threadIdx.x;
        if (e < nE) {
            int d = dst[e];
            if (d >= lo && d < hi) atomicAdd(&deg[d], 1);
        }
    }
}

__global__ __launch_bounds__(1024) void k_scan_blk(const int* __restrict__ deg, int* __restrict__ rowptr,
                                                   int* __restrict__ bsum, int n) {
    __shared__ int wsum[16];
    int tid = threadIdx.x, lane = tid & 63, wid = tid >> 6;
    int i = blockIdx.x * 1024 + tid;
    int v = (i < n) ? deg[i] : 0;
    int incl = v;
    #pragma unroll
    for (int d = 1; d < 64; d <<= 1) {
        int t = __shfl_up(incl, d, 64);
        if (lane >= d) incl += t;
    }
    if (lane == 63) wsum[wid] = incl;
    __syncthreads();
    int wo = 0;
    #pragma unroll
    for (int w = 0; w < 16; ++w) wo += (w < wid) ? wsum[w] : 0;
    if (i < n) rowptr[i + 1] = wo + incl;
    if (tid == 1023) bsum[blockIdx.x] = wo + incl;
}

// scan bsum in-register per block (nb <= 49 < 64), then add offsets
__global__ __launch_bounds__(1024) void k_scan_add(int* __restrict__ rowptr, const int* __restrict__ bsum,
                                                   int n, int nb) {
    __shared__ int soff;
    int tid = threadIdx.x;
    if (tid < 64) {
        int v = (tid < nb) ? bsum[tid] : 0;
        int incl = v;
        #pragma unroll
        for (int d = 1; d < 64; d <<= 1) {
            int t = __shfl_up(incl, d, 64);
            if (tid >= d) incl += t;
        }
        if (tid == blockIdx.x) soff = incl - v;   // exclusive prefix for this block
    }
    __syncthreads();
    int i = blockIdx.x * 1024 + tid;
    if (i == 0) rowptr[0] = 0;
    if (i < n) rowptr[i + 1] += soff;
}

__global__ __launch_bounds__(256) void k_fill_x(const int* __restrict__ src, const int* __restrict__ dst,
                                                const int* __restrict__ rowptr, int* __restrict__ deg,
                                                u16* __restrict__ esrc, int nE) {
    int r    = blockIdx.x & (NR - 1);
    int base = (blockIdx.x >> 3) * 4096;
    int lo   = r * RNG, hi = lo + RNG;
    #pragma unroll
    for (int it = 0; it < 16; ++it) {
        int e = base + it * 256 + threadIdx.x;
        if (e < nE) {
            int d = dst[e];
            if (d >= lo && d < hi) {
                int old = atomicSub(&deg[d], 1);
                esrc[rowptr[d + 1] - old] = (u16)src[e];
            }
        }
    }
}

// ---------------- merged prep: weight pack (5 layers) + x->bf16 + deg zero ----------------
struct PackArgs {
    const float* Wl[5]; const float* Wr[5];
    u16* Wh[5];
};
__global__ void k_prep(PackArgs pa, const float* __restrict__ x,
                       u32* __restrict__ oh, int* __restrict__ deg, int n64) {
    int bid = blockIdx.x;
    if (bid < 640) {                       // 5 layers x 128 blocks: weight pack
        int L   = bid >> 7;
        int idx = (bid & 127) * 256 + threadIdx.x;
        int j = idx & 7, l = (idx >> 3) & 63, s = (idx >> 9) & 7, t = idx >> 12;
        int nrow = t * 16 + (l & 15);
        int k    = s * 32 + (l >> 4) * 8 + j;
        float v  = (k < 128) ? pa.Wl[L][nrow * 128 + k] : pa.Wr[L][nrow * 128 + (k - 128)];
        pa.Wh[L][idx] = f2bf(v);
    } else {                               // x conversion + deg zeroing
        int i = (bid - 640) * 256 + threadIdx.x;
        if (i < NN) deg[i] = 0;
        if (i < n64) {
            float2 v = *(const float2*)(x + (size_t)i * 2);
            oh[i] = ((u32)f2bf(v.x)) | (((u32)f2bf(v.y)) << 16);
        }
    }
}

// ---------------- segment max over packed bf16 ----------------
#define UPK(w_, lo_, hi_) { lo_ = fmaxf(lo_, __uint_as_float((w_) << 16)); \
                            hi_ = fmaxf(hi_, __uint_as_float((w_) & 0xFFFF0000u)); }

// single plane: 16 clamped edge slots in flight per wave
__global__ __launch_bounds__(256) void k_segmax_bf(const u32* __restrict__ h2, const int* __restrict__ rowptr,
                                                   const u16* __restrict__ esrc, u32* __restrict__ agg2, int n) {
    int node = blockIdx.x * 4 + (threadIdx.x >> 6);
    int lane = threadIdx.x & 63;
    if (node >= n) return;
    int beg = rowptr[node], end = rowptr[node + 1];
    float mlo = -INFINITY, mhi = -INFINITY;
    int last = end - 1;
    for (int i = beg; i < end; i += 16) {
        u32 w[16];
        #pragma unroll
        for (int q = 0; q < 16; ++q) {
            int e = i + q; if (e > last) e = last;
            w[q] = h2[((size_t)esrc[e] << 6) + lane];
        }
        #pragma unroll
        for (int q = 0; q < 16; ++q) UPK(w[q], mlo, mhi)
    }
    u32 r = 0u;
    if (end > beg)
        r = (__float_as_uint(mlo) >> 16) | (__float_as_uint(mhi) & 0xFFFF0000u);
    __builtin_nontemporal_store(r, &agg2[(size_t)node * 64 + lane]);
}

// dual: two feature arrays over the same edges, 16 gathers in flight
__global__ __launch_bounds__(256) void k_segmax_bf2(const u32* __restrict__ hA, const u32* __restrict__ hB,
                                                    const int* __restrict__ rowptr, const u16* __restrict__ esrc,
                                                    u32* __restrict__ aggA, u32* __restrict__ aggB, int n) {
    int node = blockIdx.x * 4 + (threadIdx.x >> 6);
    int lane = threadIdx.x & 63;
    if (node >= n) return;
    int beg = rowptr[node], end = rowptr[node + 1];
    float alo = -INFINITY, ahi = -INFINITY, blo = -INFINITY, bhi = -INFINITY;
    int last = end - 1;
    for (int i = beg; i < end; i += 8) {
        size_t b[8];
        #pragma unroll
        for (int q = 0; q < 8; ++q) {
            int e = i + q; if (e > last) e = last;
            b[q] = ((size_t)esrc[e] << 6) + lane;
        }
        u32 a0 = hA[b[0]], a1 = hA[b[1]], a2 = hA[b[2]], a3 = hA[b[3]];
        u32 a4 = hA[b[4]], a5 = hA[b[5]], a6 = hA[b[6]], a7 = hA[b[7]];
        u32 q0 = hB[b[0]], q1 = hB[b[1]], q2 = hB[b[2]], q3 = hB[b[3]];
        u32 q4 = hB[b[4]], q5 = hB[b[5]], q6 = hB[b[6]], q7 = hB[b[7]];
        UPK(a0, alo, ahi) UPK(a1, alo, ahi) UPK(a2, alo, ahi) UPK(a3, alo, ahi)
        UPK(a4, alo, ahi) UPK(a5, alo, ahi) UPK(a6, alo, ahi) UPK(a7, alo, ahi)
        UPK(q0, blo, bhi) UPK(q1, blo, bhi) UPK(q2, blo, bhi) UPK(q3, blo, bhi)
        UPK(q4, blo, bhi) UPK(q5, blo, bhi) UPK(q6, blo, bhi) UPK(q7, blo, bhi)
    }
    u32 ra = 0u, rb = 0u;
    if (end > beg) {
        ra = (__float_as_uint(alo) >> 16) | (__float_as_uint(ahi) & 0xFFFF0000u);
        rb = (__float_as_uint(blo) >> 16) | (__float_as_uint(bhi) & 0xFFFF0000u);
    }
    __builtin_nontemporal_store(ra, &aggA[(size_t)node * 64 + lane]);
    __builtin_nontemporal_store(rb, &aggB[(size_t)node * 64 + lane]);
}

// ---------------- GEMM body (hi-only weights, BM=128, M=32/wave) ----------------
template<int HEAD>
__device__ __forceinline__ void gemm_body(
        const u16* __restrict__ Ahi, const u16* __restrict__ Xh,
        const u16* __restrict__ Wh, const float* __restrict__ bias,
        u32* __restrict__ outh,
        const float* __restrict__ hw, const float* __restrict__ hb,
        float* __restrict__ hout, int n, int bid, u16 (*smw)[4096]) {
    int tid  = threadIdx.x;
    int wave = tid >> 6, lane = tid & 63;
    int rit  = lane & 15, kgrp = lane >> 4;
    int m0   = bid * 128 + wave * 32;
    int ar0  = m0 + rit;      if (ar0 > n - 1) ar0 = n - 1;
    int ar1  = m0 + 16 + rit; if (ar1 > n - 1) ar1 = n - 1;

    #define STAGEH(s_, b_) do {                                                  \
        _Pragma("unroll")                                                        \
        for (int q = 0; q < 2; ++q) {                                            \
            int tt = wave * 2 + q;                                               \
            const u16* g = Wh + (((tt << 3) + (s_)) << 9) + (lane << 3);         \
            gload_lds16(g, &smw[b_][tt << 9]);                                   \
        }                                                                        \
    } while (0)

    short8 a0[4], a1[4], xh0[4], xh1[4];
    #pragma unroll
    for (int s = 0; s < 4; ++s) {
        size_t o0 = (size_t)ar0 * C + s * 32 + kgrp * 8;
        size_t o1 = (size_t)ar1 * C + s * 32 + kgrp * 8;
        a0[s]  = *(const short8*)(Ahi + o0);
        a1[s]  = *(const short8*)(Ahi + o1);
        xh0[s] = *(const short8*)(Xh + o0);
        xh1[s] = *(const short8*)(Xh + o1);
    }

    f32x4 acc0[8], acc1[8];
    #pragma unroll
    for (int t = 0; t < 8; ++t) {
        acc0[t] = (f32x4){0.f, 0.f, 0.f, 0.f};
        acc1[t] = (f32x4){0.f, 0.f, 0.f, 0.f};
    }

    STAGEH(0, 0);
    __syncthreads();

    #pragma unroll
    for (int s = 0; s < 8; ++s) {
        if (s < 7) STAGEH(s + 1, (s + 1) & 1);
        const u16* base = smw[s & 1];
        short8 f0 = (s < 4) ? a0[s] : xh0[s - 4];
        short8 f1 = (s < 4) ? a1[s] : xh1[s - 4];
        #pragma unroll
        for (int t = 0; t < 8; ++t) {
            short8 wv = *(const short8*)(base + (t << 9) + (lane << 3));
            acc0[t] = __builtin_amdgcn_mfma_f32_16x16x32_bf16(f0, wv, acc0[t], 0, 0, 0);
            acc1[t] = __builtin_amdgcn_mfma_f32_16x16x32_bf16(f1, wv, acc1[t], 0, 0, 0);
        }
        if (s < 7) __syncthreads();
    }
    #undef STAGEH

    if (HEAD) {
        float hsA[4] = {0.f, 0.f, 0.f, 0.f}, hsB[4] = {0.f, 0.f, 0.f, 0.f};
        #pragma unroll
        for (int t = 0; t < 8; ++t) {
            int col = t * 16 + rit;
            float b = bias[col], w = hw[col];
            #pragma unroll
            for (int j = 0; j < 4; ++j) {
                hsA[j] += fmaxf(acc0[t][j] + b, 0.f) * w;
                hsB[j] += fmaxf(acc1[t][j] + b, 0.f) * w;
            }
        }
        #pragma unroll
        for (int msk = 1; msk < 16; msk <<= 1) {
            #pragma unroll
            for (int j = 0; j < 4; ++j) {
                hsA[j] += __shfl_xor(hsA[j], msk, 64);
                hsB[j] += __shfl_xor(hsB[j], msk, 64);
            }
        }
        if (rit == 0) {
            float hbv = hb[0];
            #pragma unroll
            for (int j = 0; j < 4; ++j) {
                int rA = m0 + kgrp * 4 + j;
                int rB = rA + 16;
                if (rA < n) hout[rA] = hsA[j] + hbv;
                if (rB < n) hout[rB] = hsB[j] + hbv;
            }
        }
    } else {
        #pragma unroll
        for (int g = 0; g < 2; ++g) {
            int rbase = m0 + g * 16 + kgrp * 4;
            #pragma unroll
            for (int t = 0; t < 8; ++t) {
                int col = t * 16 + rit;
                float b = bias[col];
                #pragma unroll
                for (int j = 0; j < 4; ++j) {
                    int rr = rbase + j;
                    float v = fmaxf((g ? acc1[t][j] : acc0[t][j]) + b, 0.f);
                    float pv = __shfl_xor(v, 1, 64);
                    if (!(rit & 1) && rr < n)
                        outh[(size_t)rr * 64 + (col >> 1)] = ((u32)f2bf(v)) | (((u32)f2bf(pv)) << 16);
                }
            }
        }
    }
}

// L1 GEMM
__global__ __launch_bounds__(256, 2) void k_gemm_p(
        const u16* __restrict__ Ahi, const u16* __restrict__ Xh,
        const u16* __restrict__ Wh, const float* __restrict__ bias, u32* __restrict__ outh, int n) {
    __shared__ __align__(16) u16 smw[2][4096];
    gemm_body<0>(Ahi, Xh, Wh, bias, outh, nullptr, nullptr, nullptr, n, blockIdx.x, smw);
}

// merged L3 GEMMs + heads: grid = 2*GT, branch select
__global__ __launch_bounds__(256, 2) void k_gemm_heads(
        const u16* __restrict__ AhiA, const u16* __restrict__ XhA,
        const u16* __restrict__ WhA, const float* __restrict__ biasA,
        const float* __restrict__ hwA, const float* __restrict__ hbA, float* __restrict__ houtA,
        const u16* __restrict__ AhiB, const u16* __restrict__ XhB,
        const u16* __restrict__ WhB, const float* __restrict__ biasB,
        const float* __restrict__ hwB, const float* __restrict__ hbB, float* __restrict__ houtB,
        int n) {
    __shared__ __align__(16) u16 smw[2][4096];
    int nb = (n + 127) >> 7;
    int br = blockIdx.x >= nb;
    int bid = blockIdx.x - br * nb;
    gemm_body<1>(br ? AhiB : AhiA, br ? XhB : XhA, br ? WhB : WhA,
                 br ? biasB : biasA, nullptr,
                 br ? hwB : hwA, br ? hbB : hbA, br ? houtB : houtA,
                 n, bid, smw);
}

// dual-output L2: two weight sets against the same (A, X)
__global__ __launch_bounds__(256, 2) void k_gemm_p2(
        const u16* __restrict__ Ahi, const u16* __restrict__ Xh,
        const u16* __restrict__ Wh1, const float* __restrict__ b1, u32* __restrict__ out1,
        const u16* __restrict__ Wh2, const float* __restrict__ b2, u32* __restrict__ out2, int n) {
    __shared__ __align__(16) u16 smw[2][8192];  // 2 sets x 8 slices x 512 u16
    int tid  = threadIdx.x;
    int wave = tid >> 6, lane = tid & 63;
    int rit  = lane & 15, kgrp = lane >> 4;
    int m0   = blockIdx.x * 128 + wave * 32;
    int ar0  = m0 + rit;      if (ar0 > n - 1) ar0 = n - 1;
    int ar1  = m0 + 16 + rit; if (ar1 > n - 1) ar1 = n - 1;

    #define STAGE2H(s_, b_) do {                                                 \
        _Pragma("unroll")                                                        \
        for (int q = 0; q < 4; ++q) {                                            \
            int kk = wave * 4 + q;                                               \
            int set = kk >> 3, tt = kk & 7;                                      \
            const u16* g = (set ? Wh2 : Wh1) + (((tt << 3) + (s_)) << 9) + (lane << 3); \
            gload_lds16(g, &smw[b_][set * 4096 + (tt << 9)]);                    \
        }                                                                        \
    } while (0)

    short8 a0[4], a1[4], xh0[4], xh1[4];
    #pragma unroll
    for (int s = 0; s < 4; ++s) {
        size_t o0 = (size_t)ar0 * C + s * 32 + kgrp * 8;
        size_t o1 = (size_t)ar1 * C + s * 32 + kgrp * 8;
        a0[s]  = *(const short8*)(Ahi + o0);
        a1[s]  = *(const short8*)(Ahi + o1);
        xh0[s] = *(const short8*)(Xh + o0);
        xh1[s] = *(const short8*)(Xh + o1);
    }

    f32x4 accA0[8], accA1[8], accB0[8], accB1[8];
    #pragma unroll
    for (int t = 0; t < 8; ++t) {
        accA0[t] = (f32x4){0.f, 0.f, 0.f, 0.f};
        accA1[t] = (f32x4){0.f, 0.f, 0.f, 0.f};
        accB0[t] = (f32x4){0.f, 0.f, 0.f, 0.f};
        accB1[t] = (f32x4){0.f, 0.f, 0.f, 0.f};
    }

    STAGE2H(0, 0);
    __syncthreads();

    #pragma unroll
    for (int s = 0; s < 8; ++s) {
        if (s < 7) STAGE2H(s + 1, (s + 1) & 1);
        const u16* base = smw[s & 1];
        short8 f0 = (s < 4) ? a0[s] : xh0[s - 4];
        short8 f1 = (s < 4) ? a1[s] : xh1[s - 4];
        #pragma unroll
        for (int t = 0; t < 8; ++t) {
            short8 wa = *(const short8*)(base + (t << 9) + (lane << 3));
            short8 wb = *(const short8*)(base + 4096 + (t << 9) + (lane << 3));
            accA0[t] = __builtin_amdgcn_mfma_f32_16x16x32_bf16(f0, wa, accA0[t], 0, 0, 0);
            accA1[t] = __builtin_amdgcn_mfma_f32_16x16x32_bf16(f1, wa, accA1[t], 0, 0, 0);
            accB0[t] = __builtin_amdgcn_mfma_f32_16x16x32_bf16(f0, wb, accB0[t], 0, 0, 0);
            accB1[t] = __builtin_amdgcn_mfma_f32_16x16x32_bf16(f1, wb, accB1[t], 0, 0, 0);
        }
        if (s < 7) __syncthreads();
    }
    #undef STAGE2H

    #pragma unroll
    for (int e = 0; e < 2; ++e) {
        const float* bb = e ? b2 : b1;
        u32* oo = e ? out2 : out1;
        #pragma unroll
        for (int g = 0; g < 2; ++g) {
            int rbase = m0 + g * 16 + kgrp * 4;
            #pragma unroll
            for (int t = 0; t < 8; ++t) {
                int col = t * 16 + rit;
                float b = bb[col];
                #pragma unroll
                for (int j = 0; j < 4; ++j) {
                    int rr = rbase + j;
                    float acv = e ? (g ? accB1[t][j] : accB0[t][j])
                                  : (g ? accA1[t][j] : accA0[t][j]);
                    float v = fmaxf(acv + b, 0.f);
                    float pv = __shfl_xor(v, 1, 64);
                    if (!(rit & 1) && rr < n)
                        oo[(size_t)rr * 64 + (col >> 1)] = ((u32)f2bf(v)) | (((u32)f2bf(pv)) << 16);
                }
            }
        }
    }
}

// ---------------- launch ----------------

extern "C" void kernel_launch(void* const* d_in, const int* in_sizes, int n_in,
                              void* d_out, int out_size, void* d_ws, size_t ws_size,
                              hipStream_t stream) {
    const float* x     = (const float*)d_in[0];
    const int*   ei    = (const int*)d_in[1];
    const int*   src   = ei;
    const int*   dstp  = ei + NE;
    const float* sWl   = (const float*)d_in[2];
    const float* sB    = (const float*)d_in[3];
    const float* sWr   = (const float*)d_in[4];
    const float* rt1Wl = (const float*)d_in[5];
    const float* rt1B  = (const float*)d_in[6];
    const float* rt1Wr = (const float*)d_in[7];
    const float* rt2Wl = (const float*)d_in[8];
    const float* rt2B  = (const float*)d_in[9];
    const float* rt2Wr = (const float*)d_in[10];
    const float* rt3W  = (const float*)d_in[11];
    const float* rt3B  = (const float*)d_in[12];
    const float* mv1Wl = (const float*)d_in[13];
    const float* mv1B  = (const float*)d_in[14];
    const float* mv1Wr = (const float*)d_in[15];
    const float* mv2Wl = (const float*)d_in[16];
    const float* mv2B  = (const float*)d_in[17];
    const float* mv2Wr = (const float*)d_in[18];
    const float* mv3W  = (const float*)d_in[19];
    const float* mv3B  = (const float*)d_in[20];
    float* out = (float*)d_out;

    char* ws = (char*)d_ws;
    int* rowptr  = (int*)ws;                  // NN+1
    int* deg     = rowptr + (NN + 1);         // NN
    int* bsum    = deg + NN;                  // 64
    u16* esrc16  = (u16*)(bsum + 64);         // NE u16
    size_t off   = (((size_t)(NN + 1 + NN + 64) * 4 + (size_t)NE * 2) + 255) & ~(size_t)255;
    // 5 bf16 planes, each NN*64 u32 = 12.8 MB
    u32* P[5];
    for (int i = 0; i < 5; ++i) P[i] = (u32*)(ws + off) + (size_t)i * NN * 64;
    u16* wpack = (u16*)(P[4] + (size_t)NN * 64);
    u16* pk[5];
    for (int L = 0; L < 5; ++L) pk[L] = wpack + (size_t)L * 32768;

    const int NB = (NN + 1023) / 1024;
    const int GCH = ((NE + 4095) / 4096) * NR;
    const int NCVT = (NN * 64 + 255) / 256;

    // merged prep: weight pack (blocks 0..639) + x conversion + deg zeroing
    PackArgs pa;
    pa.Wl[0] = sWl;   pa.Wr[0] = sWr;
    pa.Wl[1] = rt1Wl; pa.Wr[1] = rt1Wr;
    pa.Wl[2] = rt2Wl; pa.Wr[2] = rt2Wr;
    pa.Wl[3] = mv1Wl; pa.Wr[3] = mv1Wr;
    pa.Wl[4] = mv2Wl; pa.Wr[4] = mv2Wr;
    for (int L = 0; L < 5; ++L) pa.Wh[L] = pk[L];
    k_prep<<<640 + NCVT, 256, 0, stream>>>(pa, x, P[0], deg, NN * 64);

    // CSR build (range-partitioned, XCD-affine heuristic)
    k_hist_x<<<GCH, 256, 0, stream>>>(dstp, deg, NE);
    k_scan_blk<<<NB, 1024, 0, stream>>>(deg, rowptr, bsum, NN);
    k_scan_add<<<NB, 1024, 0, stream>>>(rowptr, bsum, NN, NB);
    k_fill_x<<<GCH, 256, 0, stream>>>(src, dstp, rowptr, deg, esrc16, NE);

    dim3 gSeg((NN + 3) / 4), bSeg(256);
    const int GT = (NN + 127) / 128;

    // shared layer: agg(x)->P1; mv = relu(sage(x)) -> P2
    k_segmax_bf<<<gSeg, bSeg, 0, stream>>>(P[0], rowptr, esrc16, P[1], NN);
    k_gemm_p<<<GT, 256, 0, stream>>>((const u16*)P[1], (const u16*)P[0],
                                     pk[0], sB, P[2], NN);
    // agg(mv) -> P3; dual GEMM: rt -> P1, md -> P4
    k_segmax_bf<<<gSeg, bSeg, 0, stream>>>(P[2], rowptr, esrc16, P[3], NN);
    k_gemm_p2<<<GT, 256, 0, stream>>>((const u16*)P[3], (const u16*)P[2],
                                      pk[1], rt1B, P[1],
                                      pk[3], mv1B, P[4], NN);
    // fused dual aggregation: agg(rt) -> P0, agg(md) -> P3
    k_segmax_bf2<<<gSeg, bSeg, 0, stream>>>(P[1], P[4], rowptr, esrc16, P[0], P[3], NN);
    // merged L3 + heads (one dispatch, 2*GT blocks)
    k_gemm_heads<<<2 * GT, 256, 0, stream>>>(
        (const u16*)P[0], (const u16*)P[1], pk[2], rt2B, rt3W, rt3B, out,
        (const u16*)P[3], (const u16*)P[4], pk[4], mv2B, mv3W, mv3B, out + NN,
        NN);
}

// Round 15
// 253.334 us; speedup vs baseline: 1.6752x; 1.0174x over previous
//
#include <hip/hip_runtime.h>
#include <hip/hip_bf16.h>
#include <math.h>

#define NN 50000
#define NE 800000
#define C  128
#define NR 8            // dst ranges (XCD-affine via blockIdx%8 heuristic)
#define RNG (NN / NR)
typedef unsigned int u32;
typedef unsigned short u16;

using f32x4  = __attribute__((ext_vector_type(4))) float;
using short8 = __attribute__((ext_vector_type(8))) short;

__device__ __forceinline__ u16 f2bf(float f) {
    u32 u = __float_as_uint(f);
    u32 r = u + 0x7FFFu + ((u >> 16) & 1u);
    return (u16)(r >> 16);
}

__device__ __forceinline__ void gload_lds16(const u16* g, u16* l) {
    __builtin_amdgcn_global_load_lds(
        (const __attribute__((address_space(1))) u32*)g,
        (__attribute__((address_space(3))) u32*)l,
        16, 0, 0);
}

// ---------------- CSR build ----------------

__global__ __launch_bounds__(256) void k_hist_x(const int* __restrict__ dst, int* __restrict__ deg, int nE) {
    int r    = blockIdx.x & (NR - 1);
    int base = (blockIdx.x >> 3) * 4096;
    int lo   = r * RNG, hi = lo + RNG;
    #pragma unroll
    for (int it = 0; it < 16; ++it) {
        int e = base + it * 256 + threadIdx.x;
        if (e < nE) {
            int d = dst[e];
            if (d >= lo && d < hi) atomicAdd(&deg[d], 1);
        }
    }
}

__global__ __launch_bounds__(1024) void k_scan_blk(const int* __restrict__ deg, int* __restrict__ rowptr,
                                                   int* __restrict__ bsum, int n) {
    __shared__ int wsum[16];
    int tid = threadIdx.x, lane = tid & 63, wid = tid >> 6;
    int i = blockIdx.x * 1024 + tid;
    int v = (i < n) ? deg[i] : 0;
    int incl = v;
    #pragma unroll
    for (int d = 1; d < 64; d <<= 1) {
        int t = __shfl_up(incl, d, 64);
        if (lane >= d) incl += t;
    }
    if (lane == 63) wsum[wid] = incl;
    __syncthreads();
    int wo = 0;
    #pragma unroll
    for (int w = 0; w < 16; ++w) wo += (w < wid) ? wsum[w] : 0;
    if (i < n) rowptr[i + 1] = wo + incl;
    if (tid == 1023) bsum[blockIdx.x] = wo + incl;
}

// scan bsum in-register per block (nb <= 49 < 64), then add offsets
__global__ __launch_bounds__(1024) void k_scan_add(int* __restrict__ rowptr, const int* __restrict__ bsum,
                                                   int n, int nb) {
    __shared__ int soff;
    int tid = threadIdx.x;
    if (tid < 64) {
        int v = (tid < nb) ? bsum[tid] : 0;
        int incl = v;
        #pragma unroll
        for (int d = 1; d < 64; d <<= 1) {
            int t = __shfl_up(incl, d, 64);
            if (tid >= d) incl += t;
        }
        if (tid == blockIdx.x) soff = incl - v;   // exclusive prefix for this block
    }
    __syncthreads();
    int i = blockIdx.x * 1024 + tid;
    if (i == 0) rowptr[0] = 0;
    if (i < n) rowptr[i + 1] += soff;
}

__global__ __launch_bounds__(256) void k_fill_x(const int* __restrict__ src, const int* __restrict__ dst,
                                                const int* __restrict__ rowptr, int* __restrict__ deg,
                                                u16* __restrict__ esrc, int nE) {
    int r    = blockIdx.x & (NR - 1);
    int base = (blockIdx.x >> 3) * 4096;
    int lo   = r * RNG, hi = lo + RNG;
    #pragma unroll
    for (int it = 0; it < 16; ++it) {
        int e = base + it * 256 + threadIdx.x;
        if (e < nE) {
            int d = dst[e];
            if (d >= lo && d < hi) {
                int old = atomicSub(&deg[d], 1);
                esrc[rowptr[d + 1] - old] = (u16)src[e];
            }
        }
    }
}

// ---------------- merged prep: weight pack (5 layers) + x->bf16 + deg zero ----------------
struct PackArgs {
    const float* Wl[5]; const float* Wr[5];
    u16* Wh[5];
};
__global__ void k_prep(PackArgs pa, const float* __restrict__ x,
                       u32* __restrict__ oh, int* __restrict__ deg, int n64) {
    int bid = blockIdx.x;
    if (bid < 640) {                       // 5 layers x 128 blocks: weight pack
        int L   = bid >> 7;
        int idx = (bid & 127) * 256 + threadIdx.x;
        int j = idx & 7, l = (idx >> 3) & 63, s = (idx >> 9) & 7, t = idx >> 12;
        int nrow = t * 16 + (l & 15);
        int k    = s * 32 + (l >> 4) * 8 + j;
        float v  = (k < 128) ? pa.Wl[L][nrow * 128 + k] : pa.Wr[L][nrow * 128 + (k - 128)];
        pa.Wh[L][idx] = f2bf(v);
    } else {                               // x conversion + deg zeroing
        int i = (bid - 640) * 256 + threadIdx.x;
        if (i < NN) deg[i] = 0;
        if (i < n64) {
            float2 v = *(const float2*)(x + (size_t)i * 2);
            oh[i] = ((u32)f2bf(v.x)) | (((u32)f2bf(v.y)) << 16);
        }
    }
}

// ---------------- segment max over packed bf16 ----------------
#define UPK(w_, lo_, hi_) { lo_ = fmaxf(lo_, __uint_as_float((w_) << 16)); \
                            hi_ = fmaxf(hi_, __uint_as_float((w_) & 0xFFFF0000u)); }

// single plane: 16 clamped edge slots in flight per wave
__global__ __launch_bounds__(256) void k_segmax_bf(const u32* __restrict__ h2, const int* __restrict__ rowptr,
                                                   const u16* __restrict__ esrc, u32* __restrict__ agg2, int n) {
    int node = blockIdx.x * 4 + (threadIdx.x >> 6);
    int lane = threadIdx.x & 63;
    if (node >= n) return;
    int beg = rowptr[node], end = rowptr[node + 1];
    float mlo = -INFINITY, mhi = -INFINITY;
    int last = end - 1;
    for (int i = beg; i < end; i += 16) {
        u32 w[16];
        #pragma unroll
        for (int q = 0; q < 16; ++q) {
            int e = i + q; if (e > last) e = last;
            w[q] = h2[((size_t)esrc[e] << 6) + lane];
        }
        #pragma unroll
        for (int q = 0; q < 16; ++q) UPK(w[q], mlo, mhi)
    }
    u32 r = 0u;
    if (end > beg)
        r = (__float_as_uint(mlo) >> 16) | (__float_as_uint(mhi) & 0xFFFF0000u);
    __builtin_nontemporal_store(r, &agg2[(size_t)node * 64 + lane]);
}

// XCD-parity-split dual: blockIdx.x&1 selects the plane; under round-robin
// block->XCD mapping, each XCD gathers only ONE plane -> per-XCD L2 replication
// traffic halves. Correctness is mapping-independent.
__global__ __launch_bounds__(256) void k_segmax_bf2s(const u32* __restrict__ hA, const u32* __restrict__ hB,
                                                     const int* __restrict__ rowptr, const u16* __restrict__ esrc,
                                                     u32* __restrict__ aggA, u32* __restrict__ aggB, int n) {
    int pl   = blockIdx.x & 1;
    int node = (blockIdx.x >> 1) * 4 + (threadIdx.x >> 6);
    int lane = threadIdx.x & 63;
    if (node >= n) return;
    const u32* h2  = pl ? hB : hA;
    u32* agg2      = pl ? aggB : aggA;
    int beg = rowptr[node], end = rowptr[node + 1];
    float mlo = -INFINITY, mhi = -INFINITY;
    int last = end - 1;
    for (int i = beg; i < end; i += 16) {
        u32 w[16];
        #pragma unroll
        for (int q = 0; q < 16; ++q) {
            int e = i + q; if (e > last) e = last;
            w[q] = h2[((size_t)esrc[e] << 6) + lane];
        }
        #pragma unroll
        for (int q = 0; q < 16; ++q) UPK(w[q], mlo, mhi)
    }
    u32 r = 0u;
    if (end > beg)
        r = (__float_as_uint(mlo) >> 16) | (__float_as_uint(mhi) & 0xFFFF0000u);
    __builtin_nontemporal_store(r, &agg2[(size_t)node * 64 + lane]);
}

// ---------------- GEMM body (hi-only weights, BM=128, M=32/wave) ----------------
template<int HEAD>
__device__ __forceinline__ void gemm_body(
        const u16* __restrict__ Ahi, const u16* __restrict__ Xh,
        const u16* __restrict__ Wh, const float* __restrict__ bias,
        u32* __restrict__ outh,
        const float* __restrict__ hw, const float* __restrict__ hb,
        float* __restrict__ hout, int n, int bid, u16 (*smw)[4096]) {
    int tid  = threadIdx.x;
    int wave = tid >> 6, lane = tid & 63;
    int rit  = lane & 15, kgrp = lane >> 4;
    int m0   = bid * 128 + wave * 32;
    int ar0  = m0 + rit;      if (ar0 > n - 1) ar0 = n - 1;
    int ar1  = m0 + 16 + rit; if (ar1 > n - 1) ar1 = n - 1;

    #define STAGEH(s_, b_) do {                                                  \
        _Pragma("unroll")                                                        \
        for (int q = 0; q < 2; ++q) {                                            \
            int tt = wave * 2 + q;                                               \
            const u16* g = Wh + (((tt << 3) + (s_)) << 9) + (lane << 3);         \
            gload_lds16(g, &smw[b_][tt << 9]);                                   \
        }                                                                        \
    } while (0)

    short8 a0[4], a1[4], xh0[4], xh1[4];
    #pragma unroll
    for (int s = 0; s < 4; ++s) {
        size_t o0 = (size_t)ar0 * C + s * 32 + kgrp * 8;
        size_t o1 = (size_t)ar1 * C + s * 32 + kgrp * 8;
        a0[s]  = *(const short8*)(Ahi + o0);
        a1[s]  = *(const short8*)(Ahi + o1);
        xh0[s] = *(const short8*)(Xh + o0);
        xh1[s] = *(const short8*)(Xh + o1);
    }

    f32x4 acc0[8], acc1[8];
    #pragma unroll
    for (int t = 0; t < 8; ++t) {
        acc0[t] = (f32x4){0.f, 0.f, 0.f, 0.f};
        acc1[t] = (f32x4){0.f, 0.f, 0.f, 0.f};
    }

    STAGEH(0, 0);
    __syncthreads();

    #pragma unroll
    for (int s = 0; s < 8; ++s) {
        if (s < 7) STAGEH(s + 1, (s + 1) & 1);
        const u16* base = smw[s & 1];
        short8 f0 = (s < 4) ? a0[s] : xh0[s - 4];
        short8 f1 = (s < 4) ? a1[s] : xh1[s - 4];
        #pragma unroll
        for (int t = 0; t < 8; ++t) {
            short8 wv = *(const short8*)(base + (t << 9) + (lane << 3));
            acc0[t] = __builtin_amdgcn_mfma_f32_16x16x32_bf16(f0, wv, acc0[t], 0, 0, 0);
            acc1[t] = __builtin_amdgcn_mfma_f32_16x16x32_bf16(f1, wv, acc1[t], 0, 0, 0);
        }
        if (s < 7) __syncthreads();
    }
    #undef STAGEH

    if (HEAD) {
        float hsA[4] = {0.f, 0.f, 0.f, 0.f}, hsB[4] = {0.f, 0.f, 0.f, 0.f};
        #pragma unroll
        for (int t = 0; t < 8; ++t) {
            int col = t * 16 + rit;
            float b = bias[col], w = hw[col];
            #pragma unroll
            for (int j = 0; j < 4; ++j) {
                hsA[j] += fmaxf(acc0[t][j] + b, 0.f) * w;
                hsB[j] += fmaxf(acc1[t][j] + b, 0.f) * w;
            }
        }
        #pragma unroll
        for (int msk = 1; msk < 16; msk <<= 1) {
            #pragma unroll
            for (int j = 0; j < 4; ++j) {
                hsA[j] += __shfl_xor(hsA[j], msk, 64);
                hsB[j] += __shfl_xor(hsB[j], msk, 64);
            }
        }
        if (rit == 0) {
            float hbv = hb[0];
            #pragma unroll
            for (int j = 0; j < 4; ++j) {
                int rA = m0 + kgrp * 4 + j;
                int rB = rA + 16;
                if (rA < n) hout[rA] = hsA[j] + hbv;
                if (rB < n) hout[rB] = hsB[j] + hbv;
            }
        }
    } else {
        #pragma unroll
        for (int g = 0; g < 2; ++g) {
            int rbase = m0 + g * 16 + kgrp * 4;
            #pragma unroll
            for (int t = 0; t < 8; ++t) {
                int col = t * 16 + rit;
                float b = bias[col];
                #pragma unroll
                for (int j = 0; j < 4; ++j) {
                    int rr = rbase + j;
                    float v = fmaxf((g ? acc1[t][j] : acc0[t][j]) + b, 0.f);
                    float pv = __shfl_xor(v, 1, 64);
                    if (!(rit & 1) && rr < n)
                        outh[(size_t)rr * 64 + (col >> 1)] = ((u32)f2bf(v)) | (((u32)f2bf(pv)) << 16);
                }
            }
        }
    }
}

// L1 GEMM
__global__ __launch_bounds__(256, 2) void k_gemm_p(
        const u16* __restrict__ Ahi, const u16* __restrict__ Xh,
        const u16* __restrict__ Wh, const float* __restrict__ bias, u32* __restrict__ outh, int n) {
    __shared__ __align__(16) u16 smw[2][4096];
    gemm_body<0>(Ahi, Xh, Wh, bias, outh, nullptr, nullptr, nullptr, n, blockIdx.x, smw);
}

// merged L3 GEMMs + heads: grid = 2*GT, XCD-parity branch select
__global__ __launch_bounds__(256, 2) void k_gemm_heads(
        const u16* __restrict__ AhiA, const u16* __restrict__ XhA,
        const u16* __restrict__ WhA, const float* __restrict__ biasA,
        const float* __restrict__ hwA, const float* __restrict__ hbA, float* __restrict__ houtA,
        const u16* __restrict__ AhiB, const u16* __restrict__ XhB,
        const u16* __restrict__ WhB, const float* __restrict__ biasB,
        const float* __restrict__ hwB, const float* __restrict__ hbB, float* __restrict__ houtB,
        int n) {
    __shared__ __align__(16) u16 smw[2][4096];
    int br  = blockIdx.x & 1;        // parity -> each XCD reads one branch's planes
    int bid = blockIdx.x >> 1;
    gemm_body<1>(br ? AhiB : AhiA, br ? XhB : XhA, br ? WhB : WhA,
                 br ? biasB : biasA, nullptr,
                 br ? hwB : hwA, br ? hbB : hbA, br ? houtB : houtA,
                 n, bid, smw);
}

// dual-output L2: two weight sets against the same (A, X)
__global__ __launch_bounds__(256, 2) void k_gemm_p2(
        const u16* __restrict__ Ahi, const u16* __restrict__ Xh,
        const u16* __restrict__ Wh1, const float* __restrict__ b1, u32* __restrict__ out1,
        const u16* __restrict__ Wh2, const float* __restrict__ b2, u32* __restrict__ out2, int n) {
    __shared__ __align__(16) u16 smw[2][8192];  // 2 sets x 8 slices x 512 u16
    int tid  = threadIdx.x;
    int wave = tid >> 6, lane = tid & 63;
    int rit  = lane & 15, kgrp = lane >> 4;
    int m0   = blockIdx.x * 128 + wave * 32;
    int ar0  = m0 + rit;      if (ar0 > n - 1) ar0 = n - 1;
    int ar1  = m0 + 16 + rit; if (ar1 > n - 1) ar1 = n - 1;

    #define STAGE2H(s_, b_) do {                                                 \
        _Pragma("unroll")                                                        \
        for (int q = 0; q < 4; ++q) {                                            \
            int kk = wave * 4 + q;                                               \
            int set = kk >> 3, tt = kk & 7;                                      \
            const u16* g = (set ? Wh2 : Wh1) + (((tt << 3) + (s_)) << 9) + (lane << 3); \
            gload_lds16(g, &smw[b_][set * 4096 + (tt << 9)]);                    \
        }                                                                        \
    } while (0)

    short8 a0[4], a1[4], xh0[4], xh1[4];
    #pragma unroll
    for (int s = 0; s < 4; ++s) {
        size_t o0 = (size_t)ar0 * C + s * 32 + kgrp * 8;
        size_t o1 = (size_t)ar1 * C + s * 32 + kgrp * 8;
        a0[s]  = *(const short8*)(Ahi + o0);
        a1[s]  = *(const short8*)(Ahi + o1);
        xh0[s] = *(const short8*)(Xh + o0);
        xh1[s] = *(const short8*)(Xh + o1);
    }

    f32x4 accA0[8], accA1[8], accB0[8], accB1[8];
    #pragma unroll
    for (int t = 0; t < 8; ++t) {
        accA0[t] = (f32x4){0.f, 0.f, 0.f, 0.f};
        accA1[t] = (f32x4){0.f, 0.f, 0.f, 0.f};
        accB0[t] = (f32x4){0.f, 0.f, 0.f, 0.f};
        accB1[t] = (f32x4){0.f, 0.f, 0.f, 0.f};
    }

    STAGE2H(0, 0);
    __syncthreads();

    #pragma unroll
    for (int s = 0; s < 8; ++s) {
        if (s < 7) STAGE2H(s + 1, (s + 1) & 1);
        const u16* base = smw[s & 1];
        short8 f0 = (s < 4) ? a0[s] : xh0[s - 4];
        short8 f1 = (s < 4) ? a1[s] : xh1[s - 4];
        #pragma unroll
        for (int t = 0; t < 8; ++t) {
            short8 wa = *(const short8*)(base + (t << 9) + (lane << 3));
            short8 wb = *(const short8*)(base + 4096 + (t << 9) + (lane << 3));
            accA0[t] = __builtin_amdgcn_mfma_f32_16x16x32_bf16(f0, wa, accA0[t], 0, 0, 0);
            accA1[t] = __builtin_amdgcn_mfma_f32_16x16x32_bf16(f1, wa, accA1[t], 0, 0, 0);
            accB0[t] = __builtin_amdgcn_mfma_f32_16x16x32_bf16(f0, wb, accB0[t], 0, 0, 0);
            accB1[t] = __builtin_amdgcn_mfma_f32_16x16x32_bf16(f1, wb, accB1[t], 0, 0, 0);
        }
        if (s < 7) __syncthreads();
    }
    #undef STAGE2H

    #pragma unroll
    for (int e = 0; e < 2; ++e) {
        const float* bb = e ? b2 : b1;
        u32* oo = e ? out2 : out1;
        #pragma unroll
        for (int g = 0; g < 2; ++g) {
            int rbase = m0 + g * 16 + kgrp * 4;
            #pragma unroll
            for (int t = 0; t < 8; ++t) {
                int col = t * 16 + rit;
                float b = bb[col];
                #pragma unroll
                for (int j = 0; j < 4; ++j) {
                    int rr = rbase + j;
                    float acv = e ? (g ? accB1[t][j] : accB0[t][j])
                                  : (g ? accA1[t][j] : accA0[t][j]);
                    float v = fmaxf(acv + b, 0.f);
                    float pv = __shfl_xor(v, 1, 64);
                    if (!(rit & 1) && rr < n)
                        oo[(size_t)rr * 64 + (col >> 1)] = ((u32)f2bf(v)) | (((u32)f2bf(pv)) << 16);
                }
            }
        }
    }
}

// ---------------- launch ----------------

extern "C" void kernel_launch(void* const* d_in, const int* in_sizes, int n_in,
                              void* d_out, int out_size, void* d_ws, size_t ws_size,
                              hipStream_t stream) {
    const float* x     = (const float*)d_in[0];
    const int*   ei    = (const int*)d_in[1];
    const int*   src   = ei;
    const int*   dstp  = ei + NE;
    const float* sWl   = (const float*)d_in[2];
    const float* sB    = (const float*)d_in[3];
    const float* sWr   = (const float*)d_in[4];
    const float* rt1Wl = (const float*)d_in[5];
    const float* rt1B  = (const float*)d_in[6];
    const float* rt1Wr = (const float*)d_in[7];
    const float* rt2Wl = (const float*)d_in[8];
    const float* rt2B  = (const float*)d_in[9];
    const float* rt2Wr = (const float*)d_in[10];
    const float* rt3W  = (const float*)d_in[11];
    const float* rt3B  = (const float*)d_in[12];
    const float* mv1Wl = (const float*)d_in[13];
    const float* mv1B  = (const float*)d_in[14];
    const float* mv1Wr = (const float*)d_in[15];
    const float* mv2Wl = (const float*)d_in[16];
    const float* mv2B  = (const float*)d_in[17];
    const float* mv2Wr = (const float*)d_in[18];
    const float* mv3W  = (const float*)d_in[19];
    const float* mv3B  = (const float*)d_in[20];
    float* out = (float*)d_out;

    char* ws = (char*)d_ws;
    int* rowptr  = (int*)ws;                  // NN+1
    int* deg     = rowptr + (NN + 1);         // NN
    int* bsum    = deg + NN;                  // 64
    u16* esrc16  = (u16*)(bsum + 64);         // NE u16
    size_t off   = (((size_t)(NN + 1 + NN + 64) * 4 + (size_t)NE * 2) + 255) & ~(size_t)255;
    // 5 bf16 planes, each NN*64 u32 = 12.8 MB
    u32* P[5];
    for (int i = 0; i < 5; ++i) P[i] = (u32*)(ws + off) + (size_t)i * NN * 64;
    u16* wpack = (u16*)(P[4] + (size_t)NN * 64);
    u16* pk[5];
    for (int L = 0; L < 5; ++L) pk[L] = wpack + (size_t)L * 32768;

    const int NB = (NN + 1023) / 1024;
    const int GCH = ((NE + 4095) / 4096) * NR;
    const int NCVT = (NN * 64 + 255) / 256;

    // merged prep: weight pack (blocks 0..639) + x conversion + deg zeroing
    PackArgs pa;
    pa.Wl[0] = sWl;   pa.Wr[0] = sWr;
    pa.Wl[1] = rt1Wl; pa.Wr[1] = rt1Wr;
    pa.Wl[2] = rt2Wl; pa.Wr[2] = rt2Wr;
    pa.Wl[3] = mv1Wl; pa.Wr[3] = mv1Wr;
    pa.Wl[4] = mv2Wl; pa.Wr[4] = mv2Wr;
    for (int L = 0; L < 5; ++L) pa.Wh[L] = pk[L];
    k_prep<<<640 + NCVT, 256, 0, stream>>>(pa, x, P[0], deg, NN * 64);

    // CSR build (range-partitioned, XCD-affine heuristic)
    k_hist_x<<<GCH, 256, 0, stream>>>(dstp, deg, NE);
    k_scan_blk<<<NB, 1024, 0, stream>>>(deg, rowptr, bsum, NN);
    k_scan_add<<<NB, 1024, 0, stream>>>(rowptr, bsum, NN, NB);
    k_fill_x<<<GCH, 256, 0, stream>>>(src, dstp, rowptr, deg, esrc16, NE);

    dim3 gSeg((NN + 3) / 4), bSeg(256);
    const int GT = (NN + 127) / 128;

    // shared layer: agg(x)->P1; mv = relu(sage(x)) -> P2
    k_segmax_bf<<<gSeg, bSeg, 0, stream>>>(P[0], rowptr, esrc16, P[1], NN);
    k_gemm_p<<<GT, 256, 0, stream>>>((const u16*)P[1], (const u16*)P[0],
                                     pk[0], sB, P[2], NN);
    // agg(mv) -> P3; dual GEMM: rt -> P1, md -> P4
    k_segmax_bf<<<gSeg, bSeg, 0, stream>>>(P[2], rowptr, esrc16, P[3], NN);
    k_gemm_p2<<<GT, 256, 0, stream>>>((const u16*)P[3], (const u16*)P[2],
                                      pk[1], rt1B, P[1],
                                      pk[3], mv1B, P[4], NN);
    // XCD-parity-split dual aggregation: agg(rt) -> P0, agg(md) -> P3
    k_segmax_bf2s<<<dim3(2 * ((NN + 3) / 4)), bSeg, 0, stream>>>(
        P[1], P[4], rowptr, esrc16, P[0], P[3], NN);
    // merged L3 + heads (one dispatch, 2*GT blocks, parity branch select)
    k_gemm_heads<<<2 * GT, 256, 0, stream>>>(
        (const u16*)P[0], (const u16*)P[1], pk[2], rt2B, rt3W, rt3B, out,
        (const u16*)P[3], (const u16*)P[4], pk[4], mv2B, mv3W, mv3B, out + NN,
        NN);
}

// Round 16
// 251.326 us; speedup vs baseline: 1.6886x; 1.0080x over previous
//
#include <hip/hip_runtime.h>
#include <hip/hip_bf16.h>
#include <hip/hip_fp16.h>
#include <math.h>

#define NN 50000
#define NE 800000
#define C  128
#define NR 8            // dst ranges (XCD-affine via blockIdx%8 heuristic)
#define RNG (NN / NR)
typedef unsigned int u32;
typedef unsigned short u16;

using f32x4  = __attribute__((ext_vector_type(4))) float;
using half8  = __attribute__((ext_vector_type(8))) _Float16;
using half2v = __attribute__((ext_vector_type(2))) _Float16;

__device__ __forceinline__ u16 f2h(float f) {
    _Float16 h = (_Float16)f;
    return __builtin_bit_cast(u16, h);
}

__device__ __forceinline__ void gload_lds16(const u16* g, u16* l) {
    __builtin_amdgcn_global_load_lds(
        (const __attribute__((address_space(1))) u32*)g,
        (__attribute__((address_space(3))) u32*)l,
        16, 0, 0);
}

// ---------------- CSR build ----------------

__global__ __launch_bounds__(256) void k_hist_x(const int* __restrict__ dst, int* __restrict__ deg, int nE) {
    int r    = blockIdx.x & (NR - 1);
    int base = (blockIdx.x >> 3) * 4096;
    int lo   = r * RNG, hi = lo + RNG;
    #pragma unroll
    for (int it = 0; it < 16; ++it) {
        int e = base + it * 256 + threadIdx.x;
        if (e < nE) {
            int d = dst[e];
            if (d >= lo && d < hi) atomicAdd(&deg[d], 1);
        }
    }
}

__global__ __launch_bounds__(1024) void k_scan_blk(const int* __restrict__ deg, int* __restrict__ rowptr,
                                                   int* __restrict__ bsum, int n) {
    __shared__ int wsum[16];
    int tid = threadIdx.x, lane = tid & 63, wid = tid >> 6;
    int i = blockIdx.x * 1024 + tid;
    int v = (i < n) ? deg[i] : 0;
    int incl = v;
    #pragma unroll
    for (int d = 1; d < 64; d <<= 1) {
        int t = __shfl_up(incl, d, 64);
        if (lane >= d) incl += t;
    }
    if (lane == 63) wsum[wid] = incl;
    __syncthreads();
    int wo = 0;
    #pragma unroll
    for (int w = 0; w < 16; ++w) wo += (w < wid) ? wsum[w] : 0;
    if (i < n) rowptr[i + 1] = wo + incl;
    if (tid == 1023) bsum[blockIdx.x] = wo + incl;
}

// scan bsum in-register per block (nb <= 49 < 64), then add offsets
__global__ __launch_bounds__(1024) void k_scan_add(int* __restrict__ rowptr, const int* __restrict__ bsum,
                                                   int n, int nb) {
    __shared__ int soff;
    int tid = threadIdx.x;
    if (tid < 64) {
        int v = (tid < nb) ? bsum[tid] : 0;
        int incl = v;
        #pragma unroll
        for (int d = 1; d < 64; d <<= 1) {
            int t = __shfl_up(incl, d, 64);
            if (tid >= d) incl += t;
        }
        if (tid == blockIdx.x) soff = incl - v;   // exclusive prefix for this block
    }
    __syncthreads();
    int i = blockIdx.x * 1024 + tid;
    if (i == 0) rowptr[0] = 0;
    if (i < n) rowptr[i + 1] += soff;
}

__global__ __launch_bounds__(256) void k_fill_x(const int* __restrict__ src, const int* __restrict__ dst,
                                                const int* __restrict__ rowptr, int* __restrict__ deg,
                                                u16* __restrict__ esrc, int nE) {
    int r    = blockIdx.x & (NR - 1);
    int base = (blockIdx.x >> 3) * 4096;
    int lo   = r * RNG, hi = lo + RNG;
    #pragma unroll
    for (int it = 0; it < 16; ++it) {
        int e = base + it * 256 + threadIdx.x;
        if (e < nE) {
            int d = dst[e];
            if (d >= lo && d < hi) {
                int old = atomicSub(&deg[d], 1);
                esrc[rowptr[d + 1] - old] = (u16)src[e];
            }
        }
    }
}

// ---------------- merged prep: weight pack (5 layers, fp16) + x->fp16 + deg zero ----------------
struct PackArgs {
    const float* Wl[5]; const float* Wr[5];
    u16* Wh[5];
};
__global__ void k_prep(PackArgs pa, const float* __restrict__ x,
                       u32* __restrict__ oh, int* __restrict__ deg, int n64) {
    int bid = blockIdx.x;
    if (bid < 640) {                       // 5 layers x 128 blocks: weight pack
        int L   = bid >> 7;
        int idx = (bid & 127) * 256 + threadIdx.x;
        int j = idx & 7, l = (idx >> 3) & 63, s = (idx >> 9) & 7, t = idx >> 12;
        int nrow = t * 16 + (l & 15);
        int k    = s * 32 + (l >> 4) * 8 + j;
        float v  = (k < 128) ? pa.Wl[L][nrow * 128 + k] : pa.Wr[L][nrow * 128 + (k - 128)];
        pa.Wh[L][idx] = f2h(v);
    } else {                               // x conversion + deg zeroing
        int i = (bid - 640) * 256 + threadIdx.x;
        if (i < NN) deg[i] = 0;
        if (i < n64) {
            float2 v = *(const float2*)(x + (size_t)i * 2);
            oh[i] = ((u32)f2h(v.x)) | (((u32)f2h(v.y)) << 16);
        }
    }
}

// ---------------- segment max over packed fp16 (v_pk_max_f16) ----------------

// single plane: 16 clamped edge slots in flight per wave; packed max, no unpack
__global__ __launch_bounds__(256) void k_segmax_h(const u32* __restrict__ h2, const int* __restrict__ rowptr,
                                                  const u16* __restrict__ esrc, u32* __restrict__ agg2, int n) {
    int node = blockIdx.x * 4 + (threadIdx.x >> 6);
    int lane = threadIdx.x & 63;
    if (node >= n) return;
    int beg = rowptr[node], end = rowptr[node + 1];
    _Float16 ninf = (_Float16)(-INFINITY);
    half2v m = {ninf, ninf};
    int last = end - 1;
    for (int i = beg; i < end; i += 16) {
        u32 w[16];
        #pragma unroll
        for (int q = 0; q < 16; ++q) {
            int e = i + q; if (e > last) e = last;
            w[q] = h2[((size_t)esrc[e] << 6) + lane];
        }
        #pragma unroll
        for (int q = 0; q < 16; ++q)
            m = __builtin_elementwise_max(m, __builtin_bit_cast(half2v, w[q]));
    }
    u32 r = (end > beg) ? __builtin_bit_cast(u32, m) : 0u;
    __builtin_nontemporal_store(r, &agg2[(size_t)node * 64 + lane]);
}

// XCD-parity-split dual: blockIdx.x&1 selects plane -> each XCD gathers ONE plane
__global__ __launch_bounds__(256) void k_segmax_h2s(const u32* __restrict__ hA, const u32* __restrict__ hB,
                                                    const int* __restrict__ rowptr, const u16* __restrict__ esrc,
                                                    u32* __restrict__ aggA, u32* __restrict__ aggB, int n) {
    int pl   = blockIdx.x & 1;
    int node = (blockIdx.x >> 1) * 4 + (threadIdx.x >> 6);
    int lane = threadIdx.x & 63;
    if (node >= n) return;
    const u32* h2 = pl ? hB : hA;
    u32* agg2     = pl ? aggB : aggA;
    int beg = rowptr[node], end = rowptr[node + 1];
    _Float16 ninf = (_Float16)(-INFINITY);
    half2v m = {ninf, ninf};
    int last = end - 1;
    for (int i = beg; i < end; i += 16) {
        u32 w[16];
        #pragma unroll
        for (int q = 0; q < 16; ++q) {
            int e = i + q; if (e > last) e = last;
            w[q] = h2[((size_t)esrc[e] << 6) + lane];
        }
        #pragma unroll
        for (int q = 0; q < 16; ++q)
            m = __builtin_elementwise_max(m, __builtin_bit_cast(half2v, w[q]));
    }
    u32 r = (end > beg) ? __builtin_bit_cast(u32, m) : 0u;
    __builtin_nontemporal_store(r, &agg2[(size_t)node * 64 + lane]);
}

// ---------------- GEMM body (fp16 weights/activations, BM=128, M=32/wave) ----------------
template<int HEAD>
__device__ __forceinline__ void gemm_body(
        const u16* __restrict__ Ahi, const u16* __restrict__ Xh,
        const u16* __restrict__ Wh, const float* __restrict__ bias,
        u32* __restrict__ outh,
        const float* __restrict__ hw, const float* __restrict__ hb,
        float* __restrict__ hout, int n, int bid, u16 (*smw)[4096]) {
    int tid  = threadIdx.x;
    int wave = tid >> 6, lane = tid & 63;
    int rit  = lane & 15, kgrp = lane >> 4;
    int m0   = bid * 128 + wave * 32;
    int ar0  = m0 + rit;      if (ar0 > n - 1) ar0 = n - 1;
    int ar1  = m0 + 16 + rit; if (ar1 > n - 1) ar1 = n - 1;

    #define STAGEH(s_, b_) do {                                                  \
        _Pragma("unroll")                                                        \
        for (int q = 0; q < 2; ++q) {                                            \
            int tt = wave * 2 + q;                                               \
            const u16* g = Wh + (((tt << 3) + (s_)) << 9) + (lane << 3);         \
            gload_lds16(g, &smw[b_][tt << 9]);                                   \
        }                                                                        \
    } while (0)

    half8 a0[4], a1[4], xh0[4], xh1[4];
    #pragma unroll
    for (int s = 0; s < 4; ++s) {
        size_t o0 = (size_t)ar0 * C + s * 32 + kgrp * 8;
        size_t o1 = (size_t)ar1 * C + s * 32 + kgrp * 8;
        a0[s]  = *(const half8*)(Ahi + o0);
        a1[s]  = *(const half8*)(Ahi + o1);
        xh0[s] = *(const half8*)(Xh + o0);
        xh1[s] = *(const half8*)(Xh + o1);
    }

    f32x4 acc0[8], acc1[8];
    #pragma unroll
    for (int t = 0; t < 8; ++t) {
        acc0[t] = (f32x4){0.f, 0.f, 0.f, 0.f};
        acc1[t] = (f32x4){0.f, 0.f, 0.f, 0.f};
    }

    STAGEH(0, 0);
    __syncthreads();

    #pragma unroll
    for (int s = 0; s < 8; ++s) {
        if (s < 7) STAGEH(s + 1, (s + 1) & 1);
        const u16* base = smw[s & 1];
        half8 f0 = (s < 4) ? a0[s] : xh0[s - 4];
        half8 f1 = (s < 4) ? a1[s] : xh1[s - 4];
        #pragma unroll
        for (int t = 0; t < 8; ++t) {
            half8 wv = *(const half8*)(base + (t << 9) + (lane << 3));
            acc0[t] = __builtin_amdgcn_mfma_f32_16x16x32_f16(f0, wv, acc0[t], 0, 0, 0);
            acc1[t] = __builtin_amdgcn_mfma_f32_16x16x32_f16(f1, wv, acc1[t], 0, 0, 0);
        }
        if (s < 7) __syncthreads();
    }
    #undef STAGEH

    if (HEAD) {
        float hsA[4] = {0.f, 0.f, 0.f, 0.f}, hsB[4] = {0.f, 0.f, 0.f, 0.f};
        #pragma unroll
        for (int t = 0; t < 8; ++t) {
            int col = t * 16 + rit;
            float b = bias[col], w = hw[col];
            #pragma unroll
            for (int j = 0; j < 4; ++j) {
                hsA[j] += fmaxf(acc0[t][j] + b, 0.f) * w;
                hsB[j] += fmaxf(acc1[t][j] + b, 0.f) * w;
            }
        }
        #pragma unroll
        for (int msk = 1; msk < 16; msk <<= 1) {
            #pragma unroll
            for (int j = 0; j < 4; ++j) {
                hsA[j] += __shfl_xor(hsA[j], msk, 64);
                hsB[j] += __shfl_xor(hsB[j], msk, 64);
            }
        }
        if (rit == 0) {
            float hbv = hb[0];
            #pragma unroll
            for (int j = 0; j < 4; ++j) {
                int rA = m0 + kgrp * 4 + j;
                int rB = rA + 16;
                if (rA < n) hout[rA] = hsA[j] + hbv;
                if (rB < n) hout[rB] = hsB[j] + hbv;
            }
        }
    } else {
        #pragma unroll
        for (int g = 0; g < 2; ++g) {
            int rbase = m0 + g * 16 + kgrp * 4;
            #pragma unroll
            for (int t = 0; t < 8; ++t) {
                int col = t * 16 + rit;
                float b = bias[col];
                #pragma unroll
                for (int j = 0; j < 4; ++j) {
                    int rr = rbase + j;
                    float v = fmaxf((g ? acc1[t][j] : acc0[t][j]) + b, 0.f);
                    float pv = __shfl_xor(v, 1, 64);
                    if (!(rit & 1) && rr < n)
                        outh[(size_t)rr * 64 + (col >> 1)] = ((u32)f2h(v)) | (((u32)f2h(pv)) << 16);
                }
            }
        }
    }
}

// L1 GEMM
__global__ __launch_bounds__(256, 2) void k_gemm_p(
        const u16* __restrict__ Ahi, const u16* __restrict__ Xh,
        const u16* __restrict__ Wh, const float* __restrict__ bias, u32* __restrict__ outh, int n) {
    __shared__ __align__(16) u16 smw[2][4096];
    gemm_body<0>(Ahi, Xh, Wh, bias, outh, nullptr, nullptr, nullptr, n, blockIdx.x, smw);
}

// merged L3 GEMMs + heads: grid = 2*GT, XCD-parity branch select
__global__ __launch_bounds__(256, 2) void k_gemm_heads(
        const u16* __restrict__ AhiA, const u16* __restrict__ XhA,
        const u16* __restrict__ WhA, const float* __restrict__ biasA,
        const float* __restrict__ hwA, const float* __restrict__ hbA, float* __restrict__ houtA,
        const u16* __restrict__ AhiB, const u16* __restrict__ XhB,
        const u16* __restrict__ WhB, const float* __restrict__ biasB,
        const float* __restrict__ hwB, const float* __restrict__ hbB, float* __restrict__ houtB,
        int n) {
    __shared__ __align__(16) u16 smw[2][4096];
    int br  = blockIdx.x & 1;
    int bid = blockIdx.x >> 1;
    gemm_body<1>(br ? AhiB : AhiA, br ? XhB : XhA, br ? WhB : WhA,
                 br ? biasB : biasA, nullptr,
                 br ? hwB : hwA, br ? hbB : hbA, br ? houtB : houtA,
                 n, bid, smw);
}

// dual-output L2: two weight sets against the same (A, X)
__global__ __launch_bounds__(256, 2) void k_gemm_p2(
        const u16* __restrict__ Ahi, const u16* __restrict__ Xh,
        const u16* __restrict__ Wh1, const float* __restrict__ b1, u32* __restrict__ out1,
        const u16* __restrict__ Wh2, const float* __restrict__ b2, u32* __restrict__ out2, int n) {
    __shared__ __align__(16) u16 smw[2][8192];  // 2 sets x 8 slices x 512 u16
    int tid  = threadIdx.x;
    int wave = tid >> 6, lane = tid & 63;
    int rit  = lane & 15, kgrp = lane >> 4;
    int m0   = blockIdx.x * 128 + wave * 32;
    int ar0  = m0 + rit;      if (ar0 > n - 1) ar0 = n - 1;
    int ar1  = m0 + 16 + rit; if (ar1 > n - 1) ar1 = n - 1;

    #define STAGE2H(s_, b_) do {                                                 \
        _Pragma("unroll")                                                        \
        for (int q = 0; q < 4; ++q) {                                            \
            int kk = wave * 4 + q;                                               \
            int set = kk >> 3, tt = kk & 7;                                      \
            const u16* g = (set ? Wh2 : Wh1) + (((tt << 3) + (s_)) << 9) + (lane << 3); \
            gload_lds16(g, &smw[b_][set * 4096 + (tt << 9)]);                    \
        }                                                                        \
    } while (0)

    half8 a0[4], a1[4], xh0[4], xh1[4];
    #pragma unroll
    for (int s = 0; s < 4; ++s) {
        size_t o0 = (size_t)ar0 * C + s * 32 + kgrp * 8;
        size_t o1 = (size_t)ar1 * C + s * 32 + kgrp * 8;
        a0[s]  = *(const half8*)(Ahi + o0);
        a1[s]  = *(const half8*)(Ahi + o1);
        xh0[s] = *(const half8*)(Xh + o0);
        xh1[s] = *(const half8*)(Xh + o1);
    }

    f32x4 accA0[8], accA1[8], accB0[8], accB1[8];
    #pragma unroll
    for (int t = 0; t < 8; ++t) {
        accA0[t] = (f32x4){0.f, 0.f, 0.f, 0.f};
        accA1[t] = (f32x4){0.f, 0.f, 0.f, 0.f};
        accB0[t] = (f32x4){0.f, 0.f, 0.f, 0.f};
        accB1[t] = (f32x4){0.f, 0.f, 0.f, 0.f};
    }

    STAGE2H(0, 0);
    __syncthreads();

    #pragma unroll
    for (int s = 0; s < 8; ++s) {
        if (s < 7) STAGE2H(s + 1, (s + 1) & 1);
        const u16* base = smw[s & 1];
        half8 f0 = (s < 4) ? a0[s] : xh0[s - 4];
        half8 f1 = (s < 4) ? a1[s] : xh1[s - 4];
        #pragma unroll
        for (int t = 0; t < 8; ++t) {
            half8 wa = *(const half8*)(base + (t << 9) + (lane << 3));
            half8 wb = *(const half8*)(base + 4096 + (t << 9) + (lane << 3));
            accA0[t] = __builtin_amdgcn_mfma_f32_16x16x32_f16(f0, wa, accA0[t], 0, 0, 0);
            accA1[t] = __builtin_amdgcn_mfma_f32_16x16x32_f16(f1, wa, accA1[t], 0, 0, 0);
            accB0[t] = __builtin_amdgcn_mfma_f32_16x16x32_f16(f0, wb, accB0[t], 0, 0, 0);
            accB1[t] = __builtin_amdgcn_mfma_f32_16x16x32_f16(f1, wb, accB1[t], 0, 0, 0);
        }
        if (s < 7) __syncthreads();
    }
    #undef STAGE2H

    #pragma unroll
    for (int e = 0; e < 2; ++e) {
        const float* bb = e ? b2 : b1;
        u32* oo = e ? out2 : out1;
        #pragma unroll
        for (int g = 0; g < 2; ++g) {
            int rbase = m0 + g * 16 + kgrp * 4;
            #pragma unroll
            for (int t = 0; t < 8; ++t) {
                int col = t * 16 + rit;
                float b = bb[col];
                #pragma unroll
                for (int j = 0; j < 4; ++j) {
                    int rr = rbase + j;
                    float acv = e ? (g ? accB1[t][j] : accB0[t][j])
                                  : (g ? accA1[t][j] : accA0[t][j]);
                    float v = fmaxf(acv + b, 0.f);
                    float pv = __shfl_xor(v, 1, 64);
                    if (!(rit & 1) && rr < n)
                        oo[(size_t)rr * 64 + (col >> 1)] = ((u32)f2h(v)) | (((u32)f2h(pv)) << 16);
                }
            }
        }
    }
}

// ---------------- launch ----------------

extern "C" void kernel_launch(void* const* d_in, const int* in_sizes, int n_in,
                              void* d_out, int out_size, void* d_ws, size_t ws_size,
                              hipStream_t stream) {
    const float* x     = (const float*)d_in[0];
    const int*   ei    = (const int*)d_in[1];
    const int*   src   = ei;
    const int*   dstp  = ei + NE;
    const float* sWl   = (const float*)d_in[2];
    const float* sB    = (const float*)d_in[3];
    const float* sWr   = (const float*)d_in[4];
    const float* rt1Wl = (const float*)d_in[5];
    const float* rt1B  = (const float*)d_in[6];
    const float* rt1Wr = (const float*)d_in[7];
    const float* rt2Wl = (const float*)d_in[8];
    const float* rt2B  = (const float*)d_in[9];
    const float* rt2Wr = (const float*)d_in[10];
    const float* rt3W  = (const float*)d_in[11];
    const float* rt3B  = (const float*)d_in[12];
    const float* mv1Wl = (const float*)d_in[13];
    const float* mv1B  = (const float*)d_in[14];
    const float* mv1Wr = (const float*)d_in[15];
    const float* mv2Wl = (const float*)d_in[16];
    const float* mv2B  = (const float*)d_in[17];
    const float* mv2Wr = (const float*)d_in[18];
    const float* mv3W  = (const float*)d_in[19];
    const float* mv3B  = (const float*)d_in[20];
    float* out = (float*)d_out;

    char* ws = (char*)d_ws;
    int* rowptr  = (int*)ws;                  // NN+1
    int* deg     = rowptr + (NN + 1);         // NN
    int* bsum    = deg + NN;                  // 64
    u16* esrc16  = (u16*)(bsum + 64);         // NE u16
    size_t off   = (((size_t)(NN + 1 + NN + 64) * 4 + (size_t)NE * 2) + 255) & ~(size_t)255;
    // 5 fp16 planes, each NN*64 u32 = 12.8 MB
    u32* P[5];
    for (int i = 0; i < 5; ++i) P[i] = (u32*)(ws + off) + (size_t)i * NN * 64;
    u16* wpack = (u16*)(P[4] + (size_t)NN * 64);
    u16* pk[5];
    for (int L = 0; L < 5; ++L) pk[L] = wpack + (size_t)L * 32768;

    const int NB = (NN + 1023) / 1024;
    const int GCH = ((NE + 4095) / 4096) * NR;
    const int NCVT = (NN * 64 + 255) / 256;

    // merged prep: weight pack (blocks 0..639) + x conversion + deg zeroing
    PackArgs pa;
    pa.Wl[0] = sWl;   pa.Wr[0] = sWr;
    pa.Wl[1] = rt1Wl; pa.Wr[1] = rt1Wr;
    pa.Wl[2] = rt2Wl; pa.Wr[2] = rt2Wr;
    pa.Wl[3] = mv1Wl; pa.Wr[3] = mv1Wr;
    pa.Wl[4] = mv2Wl; pa.Wr[4] = mv2Wr;
    for (int L = 0; L < 5; ++L) pa.Wh[L] = pk[L];
    k_prep<<<640 + NCVT, 256, 0, stream>>>(pa, x, P[0], deg, NN * 64);

    // CSR build (range-partitioned, XCD-affine heuristic)
    k_hist_x<<<GCH, 256, 0, stream>>>(dstp, deg, NE);
    k_scan_blk<<<NB, 1024, 0, stream>>>(deg, rowptr, bsum, NN);
    k_scan_add<<<NB, 1024, 0, stream>>>(rowptr, bsum, NN, NB);
    k_fill_x<<<GCH, 256, 0, stream>>>(src, dstp, rowptr, deg, esrc16, NE);

    dim3 gSeg((NN + 3) / 4), bSeg(256);
    const int GT = (NN + 127) / 128;

    // shared layer: agg(x)->P1; mv = relu(sage(x)) -> P2
    k_segmax_h<<<gSeg, bSeg, 0, stream>>>(P[0], rowptr, esrc16, P[1], NN);
    k_gemm_p<<<GT, 256, 0, stream>>>((const u16*)P[1], (const u16*)P[0],
                                     pk[0], sB, P[2], NN);
    // agg(mv) -> P3; dual GEMM: rt -> P1, md -> P4
    k_segmax_h<<<gSeg, bSeg, 0, stream>>>(P[2], rowptr, esrc16, P[3], NN);
    k_gemm_p2<<<GT, 256, 0, stream>>>((const u16*)P[3], (const u16*)P[2],
                                      pk[1], rt1B, P[1],
                                      pk[3], mv1B, P[4], NN);
    // XCD-parity-split dual aggregation: agg(rt) -> P0, agg(md) -> P3
    k_segmax_h2s<<<dim3(2 * ((NN + 3) / 4)), bSeg, 0, stream>>>(
        P[1], P[4], rowptr, esrc16, P[0], P[3], NN);
    // merged L3 + heads (one dispatch, 2*GT blocks, parity branch select)
    k_gemm_heads<<<2 * GT, 256, 0, stream>>>(
        (const u16*)P[0], (const u16*)P[1], pk[2], rt2B, rt3W, rt3B, out,
        (const u16*)P[3], (const u16*)P[4], pk[4], mv2B, mv3W, mv3B, out + NN,
        NN);
}